// Round 1
// baseline (1267.052 us; speedup 1.0000x reference)
//
#include <hip/hip_runtime.h>
#include <stdint.h>

typedef __bf16 bf16;
typedef __bf16 bf16x4 __attribute__((ext_vector_type(4)));
typedef __bf16 bf16x8 __attribute__((ext_vector_type(8)));
typedef float f32x4 __attribute__((ext_vector_type(4)));

#define GAS __attribute__((address_space(1)))
#define LAS __attribute__((address_space(3)))

__device__ __forceinline__ void gload_lds16(const void* g, void* l) {
  __builtin_amdgcn_global_load_lds((GAS const void*)g, (LAS void*)l, 16, 0, 0);
}

// ---------------- fp32 -> bf16 convert (x) ----------------
__global__ __launch_bounds__(256) void cvt_bf16(const float* __restrict__ in,
                                                bf16* __restrict__ out, int n4) {
  int i = blockIdx.x * 256 + threadIdx.x;
  if (i >= n4) return;
  float4 v = ((const float4*)in)[i];
  bf16x4 o;
  o[0] = (bf16)v.x; o[1] = (bf16)v.y; o[2] = (bf16)v.z; o[3] = (bf16)v.w;
  ((bf16x4*)out)[i] = o;
}

// ------------- W[K][N] f32 -> Wt[N][K] bf16 (transpose+convert) -------------
__global__ __launch_bounds__(256) void tconv(const float* __restrict__ W,
                                             bf16* __restrict__ Wt, int K, int N) {
  __shared__ bf16 tile[64][65];
  const int tx = threadIdx.x & 63, ty = threadIdx.x >> 6;
  const int n0 = blockIdx.x * 64, k0 = blockIdx.y * 64;
#pragma unroll
  for (int i = 0; i < 16; ++i) {
    int kr = ty + i * 4;
    tile[kr][tx] = (bf16)W[(size_t)(k0 + kr) * N + n0 + tx];
  }
  __syncthreads();
#pragma unroll
  for (int i = 0; i < 16; ++i) {
    int nr = ty + i * 4;
    Wt[(size_t)(n0 + nr) * K + k0 + tx] = tile[tx][nr];
  }
}

// ---------------- bf16 GEMM: C[M][N] = A[M][K] @ Bt[N][K]^T ----------------
// 128x128 tile, BK=32, 4 waves (2x2), each wave 64x64 (4x4 MFMA 16x16x32).
// LDS layout is k-slot-major [kp][row][8]: linear for global_load_lds, 2-way
// bank aliasing (free) on ds_read_b128 fragment loads.
template <int OUTF32>
__global__ __launch_bounds__(256, 3) void gemm_bt(const bf16* __restrict__ A,
                                                  const bf16* __restrict__ Bt,
                                                  void* __restrict__ Cp,
                                                  const int M, const int N, const int K) {
  __shared__ __attribute__((aligned(16))) bf16 As[4096];
  __shared__ __attribute__((aligned(16))) bf16 Bs[4096];
  const int t = threadIdx.x, w = t >> 6, l = t & 63;
  const int la = l & 15, lq = l >> 4;
  const int m0 = blockIdx.y * 128, n0 = blockIdx.x * 128;
  const int wr = w >> 1, wc = w & 1;
  const int srow = t & 127, skp = t >> 7;  // staging: chunk c=t -> (kp=skp,row=srow); c=t+256 -> kp+2
  const bf16* Ag = A + (size_t)(m0 + srow) * K + skp * 8;
  const bf16* Bg = Bt + (size_t)(n0 + srow) * K + skp * 8;

  f32x4 acc[4][4] = {};

  for (int kt = 0; kt < K; kt += 32) {
    gload_lds16(Ag + kt, As + w * 512);
    gload_lds16(Ag + kt + 16, As + 2048 + w * 512);
    gload_lds16(Bg + kt, Bs + w * 512);
    gload_lds16(Bg + kt + 16, Bs + 2048 + w * 512);
    __syncthreads();
    bf16x8 af[4], bfr[4];
#pragma unroll
    for (int i = 0; i < 4; ++i) {
      af[i] = *(const bf16x8*)(As + (lq * 128 + wr * 64 + i * 16 + la) * 8);
      bfr[i] = *(const bf16x8*)(Bs + (lq * 128 + wc * 64 + i * 16 + la) * 8);
    }
#pragma unroll
    for (int mi = 0; mi < 4; ++mi)
#pragma unroll
      for (int ni = 0; ni < 4; ++ni)
        acc[mi][ni] = __builtin_amdgcn_mfma_f32_16x16x32_bf16(af[mi], bfr[ni], acc[mi][ni], 0, 0, 0);
    __syncthreads();
  }

  const int crow = m0 + wr * 64, ccol = n0 + wc * 64;
  if (OUTF32) {
    float* C = (float*)Cp;
#pragma unroll
    for (int mi = 0; mi < 4; ++mi)
#pragma unroll
      for (int ni = 0; ni < 4; ++ni)
#pragma unroll
        for (int i = 0; i < 4; ++i)
          C[(size_t)(crow + mi * 16 + lq * 4 + i) * N + ccol + ni * 16 + la] = acc[mi][ni][i];
  } else {
    bf16* C = (bf16*)Cp;
#pragma unroll
    for (int mi = 0; mi < 4; ++mi)
#pragma unroll
      for (int ni = 0; ni < 4; ++ni)
#pragma unroll
        for (int i = 0; i < 4; ++i)
          C[(size_t)(crow + mi * 16 + lq * 4 + i) * N + ccol + ni * 16 + la] = (bf16)acc[mi][ni][i];
  }
}

// ---------------- RoPE on q (in place). row = (b*S+t)*HQ + h ----------------
__global__ __launch_bounds__(256) void rope_q(bf16* __restrict__ qq, const int* __restrict__ pos) {
  const int w = threadIdx.x >> 6, l = threadIdx.x & 63;
  const int row = blockIdx.x * 4 + w;
  const int bt = row >> 4;  // HQ=16
  bf16* p = qq + (size_t)row * 256 + l * 4;
  bf16x4 xv = *(const bf16x4*)p;
  float x[4], y[4];
#pragma unroll
  for (int j = 0; j < 4; ++j) x[j] = (float)xv[j];
#pragma unroll
  for (int j = 0; j < 4; ++j) y[j] = __shfl_xor(x[j], 32, 64);
  const float posf = (float)pos[bt];
  bf16x4 ov;
#pragma unroll
  for (int j = 0; j < 4; ++j) {
    const int pr = (l & 31) * 4 + j;  // pair index 0..127
    float sv, cv;
    sincosf(posf * exp2f((float)pr * (-13.287712379549449f / 128.0f)), &sv, &cv);
    float o = x[j] * cv + ((l < 32) ? -y[j] : y[j]) * sv;
    ov[j] = (bf16)o;
  }
  *(bf16x4*)p = ov;
}

// ------------- RMSNorm + RoPE on k (in place). row = (b*S+t)*HKV + h -------------
__global__ __launch_bounds__(256) void norm_rope_k(bf16* __restrict__ kk,
                                                   const float* __restrict__ scale,
                                                   const int* __restrict__ pos) {
  const int w = threadIdx.x >> 6, l = threadIdx.x & 63;
  const int row = blockIdx.x * 4 + w;
  const int bt = row >> 3;  // HKV=8
  bf16* p = kk + (size_t)row * 256 + l * 4;
  bf16x4 xv = *(const bf16x4*)p;
  float x[4];
#pragma unroll
  for (int j = 0; j < 4; ++j) x[j] = (float)xv[j];
  float ss = x[0] * x[0] + x[1] * x[1] + x[2] * x[2] + x[3] * x[3];
#pragma unroll
  for (int m = 1; m < 64; m <<= 1) ss += __shfl_xor(ss, m, 64);
  const float r = rsqrtf(ss * (1.0f / 256.0f) + 1e-6f);
#pragma unroll
  for (int j = 0; j < 4; ++j) x[j] = x[j] * r * (1.0f + scale[l * 4 + j]);
  float y[4];
#pragma unroll
  for (int j = 0; j < 4; ++j) y[j] = __shfl_xor(x[j], 32, 64);
  const float posf = (float)pos[bt];
  bf16x4 ov;
#pragma unroll
  for (int j = 0; j < 4; ++j) {
    const int pr = (l & 31) * 4 + j;
    float sv, cv;
    sincosf(posf * exp2f((float)pr * (-13.287712379549449f / 128.0f)), &sv, &cv);
    float o = x[j] * cv + ((l < 32) ? -y[j] : y[j]) * sv;
    ov[j] = (bf16)o;
  }
  *(bf16x4*)p = ov;
}

// ---------------- RMSNorm on v (in place) ----------------
__global__ __launch_bounds__(256) void norm_v(bf16* __restrict__ vv,
                                              const float* __restrict__ scale) {
  const int w = threadIdx.x >> 6, l = threadIdx.x & 63;
  const int row = blockIdx.x * 4 + w;
  bf16* p = vv + (size_t)row * 256 + l * 4;
  bf16x4 xv = *(const bf16x4*)p;
  float x[4];
#pragma unroll
  for (int j = 0; j < 4; ++j) x[j] = (float)xv[j];
  float ss = x[0] * x[0] + x[1] * x[1] + x[2] * x[2] + x[3] * x[3];
#pragma unroll
  for (int m = 1; m < 64; m <<= 1) ss += __shfl_xor(ss, m, 64);
  const float r = rsqrtf(ss * (1.0f / 256.0f) + 1e-6f);
  bf16x4 ov;
#pragma unroll
  for (int j = 0; j < 4; ++j) ov[j] = (bf16)(x[j] * r * (1.0f + scale[l * 4 + j]));
  *(bf16x4*)p = ov;
}

// -------- v [b,t,hkv,d] -> vt [b,hkv,d,t] (tiled transpose, bf16) --------
__global__ __launch_bounds__(256) void vtrans(const bf16* __restrict__ v,
                                              bf16* __restrict__ vt) {
  __shared__ bf16 tile[64][65];
  const int tx = threadIdx.x & 63, ty = threadIdx.x >> 6;
  const int tt = blockIdx.x, dd = blockIdx.y, bh = blockIdx.z;
  const int b = bh >> 3, h = bh & 7;
#pragma unroll
  for (int i = 0; i < 16; ++i) {
    int trow = tt * 64 + ty + i * 4;
    tile[ty + i * 4][tx] = v[((size_t)(b * 2048 + trow) * 8 + h) * 256 + dd * 64 + tx];
  }
  __syncthreads();
#pragma unroll
  for (int i = 0; i < 16; ++i) {
    int drow = dd * 64 + ty + i * 4;
    vt[((size_t)(b * 8 + h) * 256 + drow) * 2048 + tt * 64 + tx] = tile[tx][ty + i * 4];
  }
}

// ---------------- flash attention (causal, GQA group=2) ----------------
// block = (qb, h, b): 128 q-rows, 8 waves, wave w owns rows [q0+16w, q0+16w+16).
// K tile [64][256] and V^T tile [256][64] staged slot-major via global_load_lds.
__global__ __launch_bounds__(512, 2) void flash_attn(const bf16* __restrict__ q,
                                                     const bf16* __restrict__ k,
                                                     const bf16* __restrict__ vt,
                                                     bf16* __restrict__ o) {
  __shared__ __attribute__((aligned(16))) bf16 Ks[16384];
  __shared__ __attribute__((aligned(16))) bf16 Vs[16384];
  __shared__ __attribute__((aligned(16))) bf16 Ps[8 * 1152];  // per-wave [16][72]
  const int t = threadIdx.x, w = t >> 6, l = t & 63;
  const int la = l & 15, lq = l >> 4;
  const int qb = blockIdx.x, h = blockIdx.y, b = blockIdx.z;
  const int hkv = h >> 1;
  const int q0 = qb * 128;
  const int rbase = q0 + w * 16;

  bf16x8 qf[8];
  {
    const bf16* qrow = q + ((size_t)((b * 2048 + rbase + la) * 16 + h)) * 256 + lq * 8;
#pragma unroll
    for (int kg = 0; kg < 8; ++kg) qf[kg] = *(const bf16x8*)(qrow + kg * 32);
  }
  f32x4 acc[16] = {};
  float mrow[4] = {-1e30f, -1e30f, -1e30f, -1e30f};
  float lrow[4] = {0.f, 0.f, 0.f, 0.f};

  const bf16* kbase = k + (size_t)b * 2048 * 2048 + hkv * 256;
  const bf16* vbase = vt + ((size_t)(b * 8 + hkv)) * 256 * 2048;
  const int nT = q0 / 64 + 2;

  for (int tti = 0; tti < nT; ++tti) {
    const int t0 = tti * 64;
    // stage K: chunk c -> (slot=c>>6, row=c&63); LDS byte 16c (linear)
#pragma unroll
    for (int i = 0; i < 4; ++i) {
      int c = i * 512 + t;
      int slot = c >> 6, r = c & 63;
      gload_lds16(kbase + (size_t)(t0 + r) * 2048 + slot * 8, Ks + i * 4096 + w * 512);
    }
    // stage V^T: chunk c -> (slot=c>>8, d=c&255)
#pragma unroll
    for (int i = 0; i < 4; ++i) {
      int c = i * 512 + t;
      int slot = c >> 8, d = c & 255;
      gload_lds16(vbase + (size_t)d * 2048 + t0 + slot * 8, Vs + i * 4096 + w * 512);
    }
    __syncthreads();
    if (t0 <= rbase + 15) {
      // QK^T: S[16 x 64]
      f32x4 s[4] = {};
#pragma unroll
      for (int n = 0; n < 4; ++n) {
        int rT = n * 16 + la;
#pragma unroll
        for (int kg = 0; kg < 8; ++kg) {
          int slot = kg * 4 + lq;
          bf16x8 kb = *(const bf16x8*)(Ks + (slot * 64 + rT) * 8);
          s[n] = __builtin_amdgcn_mfma_f32_16x16x32_bf16(qf[kg], kb, s[n], 0, 0, 0);
        }
      }
      float scalef[4];
#pragma unroll
      for (int i = 0; i < 4; ++i) {
        const int row = rbase + lq * 4 + i;
        float mx = -1e30f;
#pragma unroll
        for (int n = 0; n < 4; ++n) {
          float v = s[n][i] * 0.0625f;
          v = (t0 + n * 16 + la > row) ? -1e30f : v;
          s[n][i] = v;
          mx = fmaxf(mx, v);
        }
        mx = fmaxf(mx, __shfl_xor(mx, 1, 64));
        mx = fmaxf(mx, __shfl_xor(mx, 2, 64));
        mx = fmaxf(mx, __shfl_xor(mx, 4, 64));
        mx = fmaxf(mx, __shfl_xor(mx, 8, 64));
        const float mnew = fmaxf(mrow[i], mx);
        scalef[i] = __expf(mrow[i] - mnew);
        float ps = 0.f;
#pragma unroll
        for (int n = 0; n < 4; ++n) {
          float v = s[n][i];
          float pp = (v <= -1e29f) ? 0.f : __expf(v - mnew);
          s[n][i] = pp;
          ps += pp;
        }
        ps += __shfl_xor(ps, 1, 64);
        ps += __shfl_xor(ps, 2, 64);
        ps += __shfl_xor(ps, 4, 64);
        ps += __shfl_xor(ps, 8, 64);
        mrow[i] = mnew;
        lrow[i] = lrow[i] * scalef[i] + ps;
      }
#pragma unroll
      for (int n = 0; n < 16; ++n) {
        acc[n][0] *= scalef[0]; acc[n][1] *= scalef[1];
        acc[n][2] *= scalef[2]; acc[n][3] *= scalef[3];
      }
      // P (C-layout) -> per-wave LDS -> A-layout fragments
      bf16* pw = Ps + w * 1152;
#pragma unroll
      for (int n = 0; n < 4; ++n)
#pragma unroll
        for (int i = 0; i < 4; ++i)
          pw[(lq * 4 + i) * 72 + n * 16 + la] = (bf16)s[n][i];
#pragma unroll
      for (int kc = 0; kc < 2; ++kc) {
        bf16x8 pa = *(const bf16x8*)(pw + la * 72 + kc * 32 + lq * 8);
#pragma unroll
        for (int n = 0; n < 16; ++n) {
          int rd = n * 16 + la;
          int slot = kc * 4 + lq;
          bf16x8 vb = *(const bf16x8*)(Vs + (slot * 256 + rd) * 8);
          acc[n] = __builtin_amdgcn_mfma_f32_16x16x32_bf16(pa, vb, acc[n], 0, 0, 0);
        }
      }
    }
    __syncthreads();
  }
#pragma unroll
  for (int i = 0; i < 4; ++i) {
    const int row = rbase + lq * 4 + i;
    const float inv = 1.0f / lrow[i];
    bf16* orow = o + ((size_t)(b * 2048 + row)) * 4096 + h * 256;
#pragma unroll
    for (int n = 0; n < 16; ++n) orow[n * 16 + la] = (bf16)(acc[n][i] * inv);
  }
}

// ---------------- diagnostic fill if ws too small ----------------
__global__ void fill_err(float* o, int n) {
  int i = blockIdx.x * 256 + threadIdx.x;
  if (i < n) o[i] = 1e9f;
}

extern "C" void kernel_launch(void* const* d_in, const int* in_sizes, int n_in,
                              void* d_out, int out_size, void* d_ws, size_t ws_size,
                              hipStream_t stream) {
  const float* x = (const float*)d_in[0];
  const float* Wq = (const float*)d_in[1];
  const float* Wk = (const float*)d_in[2];
  const float* Wv = (const float*)d_in[3];
  const float* Wo = (const float*)d_in[4];
  const float* kscale = (const float*)d_in[5];
  const float* vscale = (const float*)d_in[6];
  const int* pos = (const int*)d_in[8];
  float* out = (float*)d_out;

  const size_t WS_NEED = 251658240ull;  // 240 MB
  if (ws_size < WS_NEED) {
    fill_err<<<65536, 256, 0, stream>>>(out, out_size);
    return;
  }
  char* ws = (char*)d_ws;
  bf16* x16 = (bf16*)(ws);
  bf16* wqt = (bf16*)(ws + 33554432);
  bf16* wkt = (bf16*)(ws + 67108864);
  bf16* wvt = (bf16*)(ws + 83886080);
  bf16* wot = (bf16*)(ws + 100663296);
  bf16* qb = (bf16*)(ws + 134217728);
  bf16* kb = (bf16*)(ws + 167772160);
  bf16* vb = (bf16*)(ws + 184549376);
  bf16* vtb = (bf16*)(ws + 201326592);
  bf16* ao = (bf16*)(ws + 218103808);

  // prep: bf16 conversions + weight transposes
  cvt_bf16<<<16384, 256, 0, stream>>>(x, x16, 4194304);
  tconv<<<dim3(64, 64), 256, 0, stream>>>(Wq, wqt, 4096, 4096);
  tconv<<<dim3(32, 64), 256, 0, stream>>>(Wk, wkt, 4096, 2048);
  tconv<<<dim3(32, 64), 256, 0, stream>>>(Wv, wvt, 4096, 2048);
  tconv<<<dim3(64, 64), 256, 0, stream>>>(Wo, wot, 4096, 4096);

  // QKV projections
  gemm_bt<0><<<dim3(32, 32), 256, 0, stream>>>(x16, wqt, qb, 4096, 4096, 4096);
  gemm_bt<0><<<dim3(16, 32), 256, 0, stream>>>(x16, wkt, kb, 4096, 2048, 4096);
  gemm_bt<0><<<dim3(16, 32), 256, 0, stream>>>(x16, wvt, vb, 4096, 2048, 4096);

  // norms + rope
  rope_q<<<16384, 256, 0, stream>>>(qb, pos);
  norm_rope_k<<<8192, 256, 0, stream>>>(kb, kscale, pos);
  norm_v<<<8192, 256, 0, stream>>>(vb, vscale);
  vtrans<<<dim3(32, 4, 16), 256, 0, stream>>>(vb, vtb);

  // attention
  flash_attn<<<dim3(16, 16, 2), 512, 0, stream>>>(qb, kb, vtb, ao);

  // output projection (fp32 out)
  gemm_bt<1><<<dim3(32, 32), 256, 0, stream>>>(ao, wot, out, 4096, 4096, 4096);
}

// Round 2
// 851.551 us; speedup vs baseline: 1.4879x; 1.4879x over previous
//
#include <hip/hip_runtime.h>
#include <stdint.h>

typedef __bf16 bf16;
typedef __bf16 bf16x4 __attribute__((ext_vector_type(4)));
typedef __bf16 bf16x8 __attribute__((ext_vector_type(8)));
typedef float f32x4 __attribute__((ext_vector_type(4)));

#define GAS __attribute__((address_space(1)))
#define LAS __attribute__((address_space(3)))

__device__ __forceinline__ void gload_lds16(const void* g, void* l) {
  __builtin_amdgcn_global_load_lds((GAS const void*)g, (LAS void*)l, 16, 0, 0);
}

// ---------------- fp32 -> bf16 convert (x) ----------------
__global__ __launch_bounds__(256) void cvt_bf16(const float* __restrict__ in,
                                                bf16* __restrict__ out, int n4) {
  int i = blockIdx.x * 256 + threadIdx.x;
  if (i >= n4) return;
  float4 v = ((const float4*)in)[i];
  bf16x4 o;
  o[0] = (bf16)v.x; o[1] = (bf16)v.y; o[2] = (bf16)v.z; o[3] = (bf16)v.w;
  ((bf16x4*)out)[i] = o;
}

// ------------- W[K][N] f32 -> Wt[N][K] bf16 (transpose+convert) -------------
__global__ __launch_bounds__(256) void tconv(const float* __restrict__ W,
                                             bf16* __restrict__ Wt, int K, int N) {
  __shared__ bf16 tile[64][65];
  const int tx = threadIdx.x & 63, ty = threadIdx.x >> 6;
  const int n0 = blockIdx.x * 64, k0 = blockIdx.y * 64;
#pragma unroll
  for (int i = 0; i < 16; ++i) {
    int kr = ty + i * 4;
    tile[kr][tx] = (bf16)W[(size_t)(k0 + kr) * N + n0 + tx];
  }
  __syncthreads();
#pragma unroll
  for (int i = 0; i < 16; ++i) {
    int nr = ty + i * 4;
    Wt[(size_t)(n0 + nr) * K + k0 + tx] = tile[tx][nr];
  }
}

// ---------------- bf16 GEMM: C[M][N] = A[M][K] @ Bt[N][K]^T ----------------
// 128x128 tile, BK=32, 4 waves (2x2), each wave 64x64 (4x4 MFMA 16x16x32).
// LDS tiles are row-major [128 rows][4 slots of 16B] with the source col-slot
// XOR-swizzled by (row&3); staging is coalesced (16 x 64B segments per
// wave-instruction), reads apply the matching XOR (2-way banks = free).
template <int OUTF32>
__global__ __launch_bounds__(256, 3) void gemm_bt(const bf16* __restrict__ A,
                                                  const bf16* __restrict__ Bt,
                                                  void* __restrict__ Cp,
                                                  const int M, const int N, const int K) {
  __shared__ __attribute__((aligned(16))) bf16 As[4096];
  __shared__ __attribute__((aligned(16))) bf16 Bs[4096];
  const int t = threadIdx.x, w = t >> 6, l = t & 63;
  const int la = l & 15, lq = l >> 4;
  const int m0 = blockIdx.y * 128, n0 = blockIdx.x * 128;
  const int wr = w >> 1, wc = w & 1;
  // staging: chunk c -> row = c>>2, slot = c&3, src col-slot = slot ^ (row&3)
  const int r1 = t >> 2, s1 = (t & 3) ^ (r1 & 3);
  const bf16* Ag1 = A + (size_t)(m0 + r1) * K + s1 * 8;
  const bf16* Ag2 = A + (size_t)(m0 + r1 + 64) * K + s1 * 8;  // (r1+64)&3 == r1&3
  const bf16* Bg1 = Bt + (size_t)(n0 + r1) * K + s1 * 8;
  const bf16* Bg2 = Bt + (size_t)(n0 + r1 + 64) * K + s1 * 8;
  // read: elem = row*32 + ((lq ^ (row&3))*8); row&3 == la&3 for our rows
  const int rdsl = (lq ^ (la & 3)) << 3;

  f32x4 acc[4][4] = {};

  for (int kt = 0; kt < K; kt += 32) {
    gload_lds16(Ag1 + kt, As + w * 512);
    gload_lds16(Ag2 + kt, As + 2048 + w * 512);
    gload_lds16(Bg1 + kt, Bs + w * 512);
    gload_lds16(Bg2 + kt, Bs + 2048 + w * 512);
    __syncthreads();
    bf16x8 af[4], bfr[4];
#pragma unroll
    for (int i = 0; i < 4; ++i) {
      af[i] = *(const bf16x8*)(As + (wr * 64 + i * 16 + la) * 32 + rdsl);
      bfr[i] = *(const bf16x8*)(Bs + (wc * 64 + i * 16 + la) * 32 + rdsl);
    }
#pragma unroll
    for (int mi = 0; mi < 4; ++mi)
#pragma unroll
      for (int ni = 0; ni < 4; ++ni)
        acc[mi][ni] = __builtin_amdgcn_mfma_f32_16x16x32_bf16(af[mi], bfr[ni], acc[mi][ni], 0, 0, 0);
    __syncthreads();
  }

  const int crow = m0 + wr * 64, ccol = n0 + wc * 64;
  if (OUTF32) {
    float* C = (float*)Cp;
#pragma unroll
    for (int mi = 0; mi < 4; ++mi)
#pragma unroll
      for (int ni = 0; ni < 4; ++ni)
#pragma unroll
        for (int i = 0; i < 4; ++i)
          C[(size_t)(crow + mi * 16 + lq * 4 + i) * N + ccol + ni * 16 + la] = acc[mi][ni][i];
  } else {
    bf16* C = (bf16*)Cp;
#pragma unroll
    for (int mi = 0; mi < 4; ++mi)
#pragma unroll
      for (int ni = 0; ni < 4; ++ni)
#pragma unroll
        for (int i = 0; i < 4; ++i)
          C[(size_t)(crow + mi * 16 + lq * 4 + i) * N + ccol + ni * 16 + la] = (bf16)acc[mi][ni][i];
  }
}

// ---------------- RoPE on q (in place). row = (b*S+t)*HQ + h ----------------
__global__ __launch_bounds__(256) void rope_q(bf16* __restrict__ qq, const int* __restrict__ pos) {
  const int w = threadIdx.x >> 6, l = threadIdx.x & 63;
  const int row = blockIdx.x * 4 + w;
  const int bt = row >> 4;  // HQ=16
  bf16* p = qq + (size_t)row * 256 + l * 4;
  bf16x4 xv = *(const bf16x4*)p;
  float x[4], y[4];
#pragma unroll
  for (int j = 0; j < 4; ++j) x[j] = (float)xv[j];
#pragma unroll
  for (int j = 0; j < 4; ++j) y[j] = __shfl_xor(x[j], 32, 64);
  const float posf = (float)pos[bt];
  bf16x4 ov;
#pragma unroll
  for (int j = 0; j < 4; ++j) {
    const int pr = (l & 31) * 4 + j;  // pair index 0..127
    float sv, cv;
    sincosf(posf * exp2f((float)pr * (-13.287712379549449f / 128.0f)), &sv, &cv);
    float o = x[j] * cv + ((l < 32) ? -y[j] : y[j]) * sv;
    ov[j] = (bf16)o;
  }
  *(bf16x4*)p = ov;
}

// ------------- RMSNorm + RoPE on k (in place). row = (b*S+t)*HKV + h -------------
__global__ __launch_bounds__(256) void norm_rope_k(bf16* __restrict__ kk,
                                                   const float* __restrict__ scale,
                                                   const int* __restrict__ pos) {
  const int w = threadIdx.x >> 6, l = threadIdx.x & 63;
  const int row = blockIdx.x * 4 + w;
  const int bt = row >> 3;  // HKV=8
  bf16* p = kk + (size_t)row * 256 + l * 4;
  bf16x4 xv = *(const bf16x4*)p;
  float x[4];
#pragma unroll
  for (int j = 0; j < 4; ++j) x[j] = (float)xv[j];
  float ss = x[0] * x[0] + x[1] * x[1] + x[2] * x[2] + x[3] * x[3];
#pragma unroll
  for (int m = 1; m < 64; m <<= 1) ss += __shfl_xor(ss, m, 64);
  const float r = rsqrtf(ss * (1.0f / 256.0f) + 1e-6f);
#pragma unroll
  for (int j = 0; j < 4; ++j) x[j] = x[j] * r * (1.0f + scale[l * 4 + j]);
  float y[4];
#pragma unroll
  for (int j = 0; j < 4; ++j) y[j] = __shfl_xor(x[j], 32, 64);
  const float posf = (float)pos[bt];
  bf16x4 ov;
#pragma unroll
  for (int j = 0; j < 4; ++j) {
    const int pr = (l & 31) * 4 + j;
    float sv, cv;
    sincosf(posf * exp2f((float)pr * (-13.287712379549449f / 128.0f)), &sv, &cv);
    float o = x[j] * cv + ((l < 32) ? -y[j] : y[j]) * sv;
    ov[j] = (bf16)o;
  }
  *(bf16x4*)p = ov;
}

// ---------------- RMSNorm on v (in place) ----------------
__global__ __launch_bounds__(256) void norm_v(bf16* __restrict__ vv,
                                              const float* __restrict__ scale) {
  const int w = threadIdx.x >> 6, l = threadIdx.x & 63;
  const int row = blockIdx.x * 4 + w;
  bf16* p = vv + (size_t)row * 256 + l * 4;
  bf16x4 xv = *(const bf16x4*)p;
  float x[4];
#pragma unroll
  for (int j = 0; j < 4; ++j) x[j] = (float)xv[j];
  float ss = x[0] * x[0] + x[1] * x[1] + x[2] * x[2] + x[3] * x[3];
#pragma unroll
  for (int m = 1; m < 64; m <<= 1) ss += __shfl_xor(ss, m, 64);
  const float r = rsqrtf(ss * (1.0f / 256.0f) + 1e-6f);
  bf16x4 ov;
#pragma unroll
  for (int j = 0; j < 4; ++j) ov[j] = (bf16)(x[j] * r * (1.0f + scale[l * 4 + j]));
  *(bf16x4*)p = ov;
}

// -------- v [b,t,hkv,d] -> vt [b,hkv,d,t] (tiled transpose, bf16) --------
__global__ __launch_bounds__(256) void vtrans(const bf16* __restrict__ v,
                                              bf16* __restrict__ vt) {
  __shared__ bf16 tile[64][65];
  const int tx = threadIdx.x & 63, ty = threadIdx.x >> 6;
  const int tt = blockIdx.x, dd = blockIdx.y, bh = blockIdx.z;
  const int b = bh >> 3, h = bh & 7;
#pragma unroll
  for (int i = 0; i < 16; ++i) {
    int trow = tt * 64 + ty + i * 4;
    tile[ty + i * 4][tx] = v[((size_t)(b * 2048 + trow) * 8 + h) * 256 + dd * 64 + tx];
  }
  __syncthreads();
#pragma unroll
  for (int i = 0; i < 16; ++i) {
    int drow = dd * 64 + ty + i * 4;
    vt[((size_t)(b * 8 + h) * 256 + drow) * 2048 + tt * 64 + tx] = tile[tx][ty + i * 4];
  }
}

// ---------------- flash attention (causal, GQA group=2) ----------------
// block = (qb, h, b): 128 q-rows, 8 waves, wave w owns rows [q0+16w, +16).
// K tile [64 rows][256] and V^T tile [256 rows][64] row-major in LDS with
// source-side XOR slot swizzle (slot ^ (row&7)); double-buffered with counted
// vmcnt so next-tile global_load_lds stays in flight across the barrier.
__global__ __launch_bounds__(512, 2) void flash_attn(const bf16* __restrict__ q,
                                                     const bf16* __restrict__ k,
                                                     const bf16* __restrict__ vt,
                                                     bf16* __restrict__ o) {
  __shared__ __attribute__((aligned(16))) bf16 Ks[2 * 16384];
  __shared__ __attribute__((aligned(16))) bf16 Vs[2 * 16384];
  __shared__ __attribute__((aligned(16))) bf16 Ps[8 * 1152];  // per-wave [16][72]
  const int t = threadIdx.x, w = t >> 6, l = t & 63;
  const int la = l & 15, lq = l >> 4;
  const int qb = blockIdx.x, h = blockIdx.y, b = blockIdx.z;
  const int hkv = h >> 1;
  const int q0 = qb * 128;
  const int rbase = q0 + w * 16;

  bf16x8 qf[8];
  {
    const bf16* qrow = q + ((size_t)((b * 2048 + rbase + la) * 16 + h)) * 256 + lq * 8;
#pragma unroll
    for (int kg = 0; kg < 8; ++kg) qf[kg] = *(const bf16x8*)(qrow + kg * 32);
  }
  f32x4 acc[16] = {};
  float mrow[4] = {-1e30f, -1e30f, -1e30f, -1e30f};
  float lrow[4] = {0.f, 0.f, 0.f, 0.f};

  const bf16* kbase = k + (size_t)b * 2048 * 2048 + hkv * 256;
  const bf16* vbase = vt + ((size_t)(b * 8 + hkv)) * 256 * 2048;
  const int nT = q0 / 64 + 2;

  // staging geometry: K chunk c=i*512+t -> row=c>>5, slot=c&31, src slot^(row&7)
  //                   V chunk c        -> row=c>>3, slot=c&7,  src slot^(row&7)
  const bf16* ksrc[4];
  const bf16* vsrc[4];
#pragma unroll
  for (int i = 0; i < 4; ++i) {
    int c = i * 512 + t;
    int krr = c >> 5, ksl = (c & 31) ^ (krr & 7);
    int vrr = c >> 3, vsl = (c & 7) ^ (vrr & 7);
    ksrc[i] = kbase + (size_t)krr * 2048 + ksl * 8;
    vsrc[i] = vbase + (size_t)vrr * 2048 + vsl * 8;
  }

#define STAGE(bb, tt0)                                                        \
  do {                                                                        \
    _Pragma("unroll") for (int i_ = 0; i_ < 4; ++i_)                          \
        gload_lds16(ksrc[i_] + (size_t)(tt0) * 2048,                          \
                    Ks + (bb) * 16384 + i_ * 4096 + w * 512);                 \
    _Pragma("unroll") for (int i_ = 0; i_ < 4; ++i_)                          \
        gload_lds16(vsrc[i_] + (tt0), Vs + (bb) * 16384 + i_ * 4096 + w * 512); \
  } while (0)

  STAGE(0, 0);
  int cur = 0;
  for (int tti = 0; tti < nT; ++tti) {
    const int t0 = tti * 64;
    if (tti + 1 < nT) {
      STAGE(cur ^ 1, t0 + 64);
      asm volatile("s_waitcnt vmcnt(8)" ::: "memory");  // cur's loads done, next's fly
    } else {
      asm volatile("s_waitcnt vmcnt(0)" ::: "memory");
    }
    __builtin_amdgcn_s_barrier();
    __builtin_amdgcn_sched_barrier(0);
    if (t0 <= rbase + 15) {
      const bf16* Kc = Ks + cur * 16384;
      const bf16* Vc = Vs + cur * 16384;
      // QK^T: S[16 x 64]
      f32x4 s[4] = {};
      __builtin_amdgcn_s_setprio(1);
#pragma unroll
      for (int n = 0; n < 4; ++n) {
        int rT = n * 16 + la;
#pragma unroll
        for (int kg = 0; kg < 8; ++kg) {
          int sl = (kg * 4 + lq) ^ (rT & 7);
          bf16x8 kbv = *(const bf16x8*)(Kc + rT * 256 + sl * 8);
          s[n] = __builtin_amdgcn_mfma_f32_16x16x32_bf16(qf[kg], kbv, s[n], 0, 0, 0);
        }
      }
      __builtin_amdgcn_s_setprio(0);
      float scalef[4];
#pragma unroll
      for (int i = 0; i < 4; ++i) {
        const int row = rbase + lq * 4 + i;
        float mx = -1e30f;
#pragma unroll
        for (int n = 0; n < 4; ++n) {
          float v = s[n][i] * 0.0625f;
          v = (t0 + n * 16 + la > row) ? -1e30f : v;
          s[n][i] = v;
          mx = fmaxf(mx, v);
        }
        mx = fmaxf(mx, __shfl_xor(mx, 1, 64));
        mx = fmaxf(mx, __shfl_xor(mx, 2, 64));
        mx = fmaxf(mx, __shfl_xor(mx, 4, 64));
        mx = fmaxf(mx, __shfl_xor(mx, 8, 64));
        const float mnew = fmaxf(mrow[i], mx);
        scalef[i] = __expf(mrow[i] - mnew);
        float ps = 0.f;
#pragma unroll
        for (int n = 0; n < 4; ++n) {
          float v = s[n][i];
          float pp = (v <= -1e29f) ? 0.f : __expf(v - mnew);
          s[n][i] = pp;
          ps += pp;
        }
        ps += __shfl_xor(ps, 1, 64);
        ps += __shfl_xor(ps, 2, 64);
        ps += __shfl_xor(ps, 4, 64);
        ps += __shfl_xor(ps, 8, 64);
        mrow[i] = mnew;
        lrow[i] = lrow[i] * scalef[i] + ps;
      }
#pragma unroll
      for (int n = 0; n < 16; ++n) {
        acc[n][0] *= scalef[0]; acc[n][1] *= scalef[1];
        acc[n][2] *= scalef[2]; acc[n][3] *= scalef[3];
      }
      // P (C-layout) -> per-wave LDS -> A-layout fragments
      bf16* pw = Ps + w * 1152;
#pragma unroll
      for (int n = 0; n < 4; ++n)
#pragma unroll
        for (int i = 0; i < 4; ++i)
          pw[(lq * 4 + i) * 72 + n * 16 + la] = (bf16)s[n][i];
      __builtin_amdgcn_s_setprio(1);
#pragma unroll
      for (int kc = 0; kc < 2; ++kc) {
        bf16x8 pa = *(const bf16x8*)(pw + la * 72 + kc * 32 + lq * 8);
#pragma unroll
        for (int n = 0; n < 16; ++n) {
          int rd = n * 16 + la;
          int sl = (kc * 4 + lq) ^ (rd & 7);
          bf16x8 vbv = *(const bf16x8*)(Vc + rd * 64 + sl * 8);
          acc[n] = __builtin_amdgcn_mfma_f32_16x16x32_bf16(pa, vbv, acc[n], 0, 0, 0);
        }
      }
      __builtin_amdgcn_s_setprio(0);
    }
    __builtin_amdgcn_s_barrier();
    __builtin_amdgcn_sched_barrier(0);
    cur ^= 1;
  }
#undef STAGE
#pragma unroll
  for (int i = 0; i < 4; ++i) {
    const int row = rbase + lq * 4 + i;
    const float inv = 1.0f / lrow[i];
    bf16* orow = o + ((size_t)(b * 2048 + row)) * 4096 + h * 256;
#pragma unroll
    for (int n = 0; n < 16; ++n) orow[n * 16 + la] = (bf16)(acc[n][i] * inv);
  }
}

// ---------------- diagnostic fill if ws too small ----------------
__global__ void fill_err(float* o, int n) {
  int i = blockIdx.x * 256 + threadIdx.x;
  if (i < n) o[i] = 1e9f;
}

extern "C" void kernel_launch(void* const* d_in, const int* in_sizes, int n_in,
                              void* d_out, int out_size, void* d_ws, size_t ws_size,
                              hipStream_t stream) {
  const float* x = (const float*)d_in[0];
  const float* Wq = (const float*)d_in[1];
  const float* Wk = (const float*)d_in[2];
  const float* Wv = (const float*)d_in[3];
  const float* Wo = (const float*)d_in[4];
  const float* kscale = (const float*)d_in[5];
  const float* vscale = (const float*)d_in[6];
  const int* pos = (const int*)d_in[8];
  float* out = (float*)d_out;

  const size_t WS_NEED = 251658240ull;  // 240 MB
  if (ws_size < WS_NEED) {
    fill_err<<<65536, 256, 0, stream>>>(out, out_size);
    return;
  }
  char* ws = (char*)d_ws;
  bf16* x16 = (bf16*)(ws);
  bf16* wqt = (bf16*)(ws + 33554432);
  bf16* wkt = (bf16*)(ws + 67108864);
  bf16* wvt = (bf16*)(ws + 83886080);
  bf16* wot = (bf16*)(ws + 100663296);
  bf16* qb = (bf16*)(ws + 134217728);
  bf16* kb = (bf16*)(ws + 167772160);
  bf16* vb = (bf16*)(ws + 184549376);
  bf16* vtb = (bf16*)(ws + 201326592);
  bf16* ao = (bf16*)(ws + 218103808);

  // prep: bf16 conversions + weight transposes
  cvt_bf16<<<16384, 256, 0, stream>>>(x, x16, 4194304);
  tconv<<<dim3(64, 64), 256, 0, stream>>>(Wq, wqt, 4096, 4096);
  tconv<<<dim3(32, 64), 256, 0, stream>>>(Wk, wkt, 4096, 2048);
  tconv<<<dim3(32, 64), 256, 0, stream>>>(Wv, wvt, 4096, 2048);
  tconv<<<dim3(64, 64), 256, 0, stream>>>(Wo, wot, 4096, 4096);

  // QKV projections
  gemm_bt<0><<<dim3(32, 32), 256, 0, stream>>>(x16, wqt, qb, 4096, 4096, 4096);
  gemm_bt<0><<<dim3(16, 32), 256, 0, stream>>>(x16, wkt, kb, 4096, 2048, 4096);
  gemm_bt<0><<<dim3(16, 32), 256, 0, stream>>>(x16, wvt, vb, 4096, 2048, 4096);

  // norms + rope
  rope_q<<<16384, 256, 0, stream>>>(qb, pos);
  norm_rope_k<<<8192, 256, 0, stream>>>(kb, kscale, pos);
  norm_v<<<8192, 256, 0, stream>>>(vb, vscale);
  vtrans<<<dim3(32, 4, 16), 256, 0, stream>>>(vb, vtb);

  // attention
  flash_attn<<<dim3(16, 16, 2), 512, 0, stream>>>(qb, kb, vtb, ao);

  // output projection (fp32 out)
  gemm_bt<1><<<dim3(32, 32), 256, 0, stream>>>(ao, wot, out, 4096, 4096, 4096);
}

// Round 3
// 744.045 us; speedup vs baseline: 1.7029x; 1.1445x over previous
//
#include <hip/hip_runtime.h>
#include <stdint.h>

typedef __bf16 bf16;
typedef __bf16 bf16x4 __attribute__((ext_vector_type(4)));
typedef __bf16 bf16x8 __attribute__((ext_vector_type(8)));
typedef float f32x4 __attribute__((ext_vector_type(4)));

#define GAS __attribute__((address_space(1)))
#define LAS __attribute__((address_space(3)))

__device__ __forceinline__ void gload_lds16(const void* g, void* l) {
  __builtin_amdgcn_global_load_lds((GAS const void*)g, (LAS void*)l, 16, 0, 0);
}

// ---------------- fp32 -> bf16 convert (x) ----------------
__global__ __launch_bounds__(256) void cvt_bf16(const float* __restrict__ in,
                                                bf16* __restrict__ out, int n4) {
  int i = blockIdx.x * 256 + threadIdx.x;
  if (i >= n4) return;
  float4 v = ((const float4*)in)[i];
  bf16x4 o;
  o[0] = (bf16)v.x; o[1] = (bf16)v.y; o[2] = (bf16)v.z; o[3] = (bf16)v.w;
  ((bf16x4*)out)[i] = o;
}

// ------------- W[K][N] f32 -> Wt[N][K] bf16 (transpose+convert) -------------
__global__ __launch_bounds__(256) void tconv(const float* __restrict__ W,
                                             bf16* __restrict__ Wt, int K, int N) {
  __shared__ bf16 tile[64][65];
  const int tx = threadIdx.x & 63, ty = threadIdx.x >> 6;
  const int n0 = blockIdx.x * 64, k0 = blockIdx.y * 64;
#pragma unroll
  for (int i = 0; i < 16; ++i) {
    int kr = ty + i * 4;
    tile[kr][tx] = (bf16)W[(size_t)(k0 + kr) * N + n0 + tx];
  }
  __syncthreads();
#pragma unroll
  for (int i = 0; i < 16; ++i) {
    int nr = ty + i * 4;
    Wt[(size_t)(n0 + nr) * K + k0 + tx] = tile[tx][nr];
  }
}

// ---------------- bf16 GEMM: C[M][N] = A[M][K] @ Bt[N][K]^T ----------------
// 128x128 tile, BK=32, 4 waves (2x2), each wave 64x64 (4x4 MFMA 16x16x32).
template <int OUTF32>
__global__ __launch_bounds__(256, 3) void gemm_bt(const bf16* __restrict__ A,
                                                  const bf16* __restrict__ Bt,
                                                  void* __restrict__ Cp,
                                                  const int M, const int N, const int K) {
  __shared__ __attribute__((aligned(16))) bf16 As[4096];
  __shared__ __attribute__((aligned(16))) bf16 Bs[4096];
  const int t = threadIdx.x, w = t >> 6, l = t & 63;
  const int la = l & 15, lq = l >> 4;
  const int m0 = blockIdx.y * 128, n0 = blockIdx.x * 128;
  const int wr = w >> 1, wc = w & 1;
  // staging: chunk c -> row = c>>2, slot = c&3, src col-slot = slot ^ (row&3)
  const int r1 = t >> 2, s1 = (t & 3) ^ (r1 & 3);
  const bf16* Ag1 = A + (size_t)(m0 + r1) * K + s1 * 8;
  const bf16* Ag2 = A + (size_t)(m0 + r1 + 64) * K + s1 * 8;
  const bf16* Bg1 = Bt + (size_t)(n0 + r1) * K + s1 * 8;
  const bf16* Bg2 = Bt + (size_t)(n0 + r1 + 64) * K + s1 * 8;
  const int rdsl = (lq ^ (la & 3)) << 3;

  f32x4 acc[4][4] = {};

  for (int kt = 0; kt < K; kt += 32) {
    gload_lds16(Ag1 + kt, As + w * 512);
    gload_lds16(Ag2 + kt, As + 2048 + w * 512);
    gload_lds16(Bg1 + kt, Bs + w * 512);
    gload_lds16(Bg2 + kt, Bs + 2048 + w * 512);
    __syncthreads();
    bf16x8 af[4], bfr[4];
#pragma unroll
    for (int i = 0; i < 4; ++i) {
      af[i] = *(const bf16x8*)(As + (wr * 64 + i * 16 + la) * 32 + rdsl);
      bfr[i] = *(const bf16x8*)(Bs + (wc * 64 + i * 16 + la) * 32 + rdsl);
    }
#pragma unroll
    for (int mi = 0; mi < 4; ++mi)
#pragma unroll
      for (int ni = 0; ni < 4; ++ni)
        acc[mi][ni] = __builtin_amdgcn_mfma_f32_16x16x32_bf16(af[mi], bfr[ni], acc[mi][ni], 0, 0, 0);
    __syncthreads();
  }

  const int crow = m0 + wr * 64, ccol = n0 + wc * 64;
  if (OUTF32) {
    float* C = (float*)Cp;
#pragma unroll
    for (int mi = 0; mi < 4; ++mi)
#pragma unroll
      for (int ni = 0; ni < 4; ++ni)
#pragma unroll
        for (int i = 0; i < 4; ++i)
          C[(size_t)(crow + mi * 16 + lq * 4 + i) * N + ccol + ni * 16 + la] = acc[mi][ni][i];
  } else {
    bf16* C = (bf16*)Cp;
#pragma unroll
    for (int mi = 0; mi < 4; ++mi)
#pragma unroll
      for (int ni = 0; ni < 4; ++ni)
#pragma unroll
        for (int i = 0; i < 4; ++i)
          C[(size_t)(crow + mi * 16 + lq * 4 + i) * N + ccol + ni * 16 + la] = (bf16)acc[mi][ni][i];
  }
}

// ---------------- RoPE on q (in place, + fold in 1/sqrt(HD) score scale) ----------------
__global__ __launch_bounds__(256) void rope_q(bf16* __restrict__ qq, const int* __restrict__ pos) {
  const int w = threadIdx.x >> 6, l = threadIdx.x & 63;
  const int row = blockIdx.x * 4 + w;
  const int bt = row >> 4;  // HQ=16
  bf16* p = qq + (size_t)row * 256 + l * 4;
  bf16x4 xv = *(const bf16x4*)p;
  float x[4], y[4];
#pragma unroll
  for (int j = 0; j < 4; ++j) x[j] = (float)xv[j];
#pragma unroll
  for (int j = 0; j < 4; ++j) y[j] = __shfl_xor(x[j], 32, 64);
  const float posf = (float)pos[bt];
  bf16x4 ov;
#pragma unroll
  for (int j = 0; j < 4; ++j) {
    const int pr = (l & 31) * 4 + j;  // pair index 0..127
    float sv, cv;
    sincosf(posf * exp2f((float)pr * (-13.287712379549449f / 128.0f)), &sv, &cv);
    float o = x[j] * cv + ((l < 32) ? -y[j] : y[j]) * sv;
    ov[j] = (bf16)(o * 0.0625f);  // 1/sqrt(256), exact pow2
  }
  *(bf16x4*)p = ov;
}

// ------------- RMSNorm + RoPE on k (in place). row = (b*S+t)*HKV + h -------------
__global__ __launch_bounds__(256) void norm_rope_k(bf16* __restrict__ kk,
                                                   const float* __restrict__ scale,
                                                   const int* __restrict__ pos) {
  const int w = threadIdx.x >> 6, l = threadIdx.x & 63;
  const int row = blockIdx.x * 4 + w;
  const int bt = row >> 3;  // HKV=8
  bf16* p = kk + (size_t)row * 256 + l * 4;
  bf16x4 xv = *(const bf16x4*)p;
  float x[4];
#pragma unroll
  for (int j = 0; j < 4; ++j) x[j] = (float)xv[j];
  float ss = x[0] * x[0] + x[1] * x[1] + x[2] * x[2] + x[3] * x[3];
#pragma unroll
  for (int m = 1; m < 64; m <<= 1) ss += __shfl_xor(ss, m, 64);
  const float r = rsqrtf(ss * (1.0f / 256.0f) + 1e-6f);
#pragma unroll
  for (int j = 0; j < 4; ++j) x[j] = x[j] * r * (1.0f + scale[l * 4 + j]);
  float y[4];
#pragma unroll
  for (int j = 0; j < 4; ++j) y[j] = __shfl_xor(x[j], 32, 64);
  const float posf = (float)pos[bt];
  bf16x4 ov;
#pragma unroll
  for (int j = 0; j < 4; ++j) {
    const int pr = (l & 31) * 4 + j;
    float sv, cv;
    sincosf(posf * exp2f((float)pr * (-13.287712379549449f / 128.0f)), &sv, &cv);
    float o = x[j] * cv + ((l < 32) ? -y[j] : y[j]) * sv;
    ov[j] = (bf16)o;
  }
  *(bf16x4*)p = ov;
}

// ---------------- RMSNorm on v (in place) ----------------
__global__ __launch_bounds__(256) void norm_v(bf16* __restrict__ vv,
                                              const float* __restrict__ scale) {
  const int w = threadIdx.x >> 6, l = threadIdx.x & 63;
  const int row = blockIdx.x * 4 + w;
  bf16* p = vv + (size_t)row * 256 + l * 4;
  bf16x4 xv = *(const bf16x4*)p;
  float x[4];
#pragma unroll
  for (int j = 0; j < 4; ++j) x[j] = (float)xv[j];
  float ss = x[0] * x[0] + x[1] * x[1] + x[2] * x[2] + x[3] * x[3];
#pragma unroll
  for (int m = 1; m < 64; m <<= 1) ss += __shfl_xor(ss, m, 64);
  const float r = rsqrtf(ss * (1.0f / 256.0f) + 1e-6f);
  bf16x4 ov;
#pragma unroll
  for (int j = 0; j < 4; ++j) ov[j] = (bf16)(x[j] * r * (1.0f + scale[l * 4 + j]));
  *(bf16x4*)p = ov;
}

// -------- v [b,t,hkv,d] -> vt [b,hkv,d,t] (tiled transpose, bf16) --------
__global__ __launch_bounds__(256) void vtrans(const bf16* __restrict__ v,
                                              bf16* __restrict__ vt) {
  __shared__ bf16 tile[64][65];
  const int tx = threadIdx.x & 63, ty = threadIdx.x >> 6;
  const int tt = blockIdx.x, dd = blockIdx.y, bh = blockIdx.z;
  const int b = bh >> 3, h = bh & 7;
#pragma unroll
  for (int i = 0; i < 16; ++i) {
    int trow = tt * 64 + ty + i * 4;
    tile[ty + i * 4][tx] = v[((size_t)(b * 2048 + trow) * 8 + h) * 256 + dd * 64 + tx];
  }
  __syncthreads();
#pragma unroll
  for (int i = 0; i < 16; ++i) {
    int drow = dd * 64 + ty + i * 4;
    vt[((size_t)(b * 8 + h) * 256 + drow) * 2048 + tt * 64 + tx] = tile[tx][ty + i * 4];
  }
}

// ---------------- flash attention (causal, GQA group=2) ----------------
// block = (h, qbp, b): processes the qb pair {15-qbp, qbp} sequentially so all
// 256 blocks do exactly 34 K/V tiles (load-balanced, 1 block/CU). grid.x = h
// so the 8 qbp-blocks sharing one (hkv,b) K/V stream land on the same XCD-L2.
__global__ __launch_bounds__(512, 2) void flash_attn(const bf16* __restrict__ q,
                                                     const bf16* __restrict__ k,
                                                     const bf16* __restrict__ vt,
                                                     bf16* __restrict__ o) {
  __shared__ __attribute__((aligned(16))) bf16 Ks[2 * 16384];
  __shared__ __attribute__((aligned(16))) bf16 Vs[2 * 16384];
  __shared__ __attribute__((aligned(16))) bf16 Ps[8 * 1152];  // per-wave [16][72]
  const int t = threadIdx.x, w = t >> 6, l = t & 63;
  const int la = l & 15, lq = l >> 4;
  const int h = blockIdx.x, qbp = blockIdx.y, b = blockIdx.z;
  const int hkv = h >> 1;

  const bf16* kbase = k + (size_t)b * 2048 * 2048 + hkv * 256;
  const bf16* vbase = vt + ((size_t)(b * 8 + hkv)) * 256 * 2048;

  // staging geometry: K chunk c=i*512+t -> row=c>>5, slot=c&31, src slot^(row&7)
  //                   V chunk c        -> row=c>>3, slot=c&7,  src slot^(row&7)
  const bf16* ksrc[4];
  const bf16* vsrc[4];
#pragma unroll
  for (int i = 0; i < 4; ++i) {
    int c = i * 512 + t;
    int krr = c >> 5, ksl = (c & 31) ^ (krr & 7);
    int vrr = c >> 3, vsl = (c & 7) ^ (vrr & 7);
    ksrc[i] = kbase + (size_t)krr * 2048 + ksl * 8;
    vsrc[i] = vbase + (size_t)vrr * 2048 + vsl * 8;
  }

#define STAGE(bb, tt0)                                                        \
  do {                                                                        \
    _Pragma("unroll") for (int i_ = 0; i_ < 4; ++i_)                          \
        gload_lds16(ksrc[i_] + (size_t)(tt0) * 2048,                          \
                    Ks + (bb) * 16384 + i_ * 4096 + w * 512);                 \
    _Pragma("unroll") for (int i_ = 0; i_ < 4; ++i_)                          \
        gload_lds16(vsrc[i_] + (tt0), Vs + (bb) * 16384 + i_ * 4096 + w * 512); \
  } while (0)

  for (int part = 0; part < 2; ++part) {
    const int qb = part ? qbp : (15 - qbp);
    const int q0 = qb * 128;
    const int rbase = q0 + w * 16;

    bf16x8 qf[8];
    {
      const bf16* qrow = q + ((size_t)((b * 2048 + rbase + la) * 16 + h)) * 256 + lq * 8;
#pragma unroll
      for (int kg = 0; kg < 8; ++kg) qf[kg] = *(const bf16x8*)(qrow + kg * 32);
    }
    f32x4 acc[16] = {};
    float mrow[4] = {-1e30f, -1e30f, -1e30f, -1e30f};
    float lrow[4] = {0.f, 0.f, 0.f, 0.f};
    const int nT = 2 * qb + 2;

    STAGE(0, 0);
    int cur = 0;
    for (int tti = 0; tti < nT; ++tti) {
      const int t0 = tti * 64;
      if (tti + 1 < nT) {
        STAGE(cur ^ 1, t0 + 64);
        asm volatile("s_waitcnt vmcnt(8)" ::: "memory");  // cur landed, next flies
      } else {
        asm volatile("s_waitcnt vmcnt(0)" ::: "memory");
      }
      __builtin_amdgcn_s_barrier();
      __builtin_amdgcn_sched_barrier(0);
      if (t0 <= rbase + 15) {
        const bf16* Kc = Ks + cur * 16384;
        const bf16* Vc = Vs + cur * 16384;
        // QK^T: S[16 x 64]
        f32x4 s[4] = {};
        __builtin_amdgcn_s_setprio(1);
#pragma unroll
        for (int n = 0; n < 4; ++n) {
          int rT = n * 16 + la;
#pragma unroll
          for (int kg = 0; kg < 8; ++kg) {
            int sl = (kg * 4 + lq) ^ (rT & 7);
            bf16x8 kbv = *(const bf16x8*)(Kc + rT * 256 + sl * 8);
            s[n] = __builtin_amdgcn_mfma_f32_16x16x32_bf16(qf[kg], kbv, s[n], 0, 0, 0);
          }
        }
        __builtin_amdgcn_s_setprio(0);
        float scalef[4];
#pragma unroll
        for (int i = 0; i < 4; ++i) {
          const int row = rbase + lq * 4 + i;
          float mx = -1e30f;
#pragma unroll
          for (int n = 0; n < 4; ++n) {
            float v = s[n][i];
            v = (t0 + n * 16 + la > row) ? -1e30f : v;
            s[n][i] = v;
            mx = fmaxf(mx, v);
          }
          mx = fmaxf(mx, __shfl_xor(mx, 1, 64));
          mx = fmaxf(mx, __shfl_xor(mx, 2, 64));
          mx = fmaxf(mx, __shfl_xor(mx, 4, 64));
          mx = fmaxf(mx, __shfl_xor(mx, 8, 64));
          const float mnew = fmaxf(mrow[i], mx);
          scalef[i] = __expf(mrow[i] - mnew);
          float ps = 0.f;
#pragma unroll
          for (int n = 0; n < 4; ++n) {
            float v = s[n][i];
            float pp = (v <= -1e29f) ? 0.f : __expf(v - mnew);
            s[n][i] = pp;
            ps += pp;
          }
          ps += __shfl_xor(ps, 1, 64);
          ps += __shfl_xor(ps, 2, 64);
          ps += __shfl_xor(ps, 4, 64);
          ps += __shfl_xor(ps, 8, 64);
          mrow[i] = mnew;
          lrow[i] = lrow[i] * scalef[i] + ps;
        }
#pragma unroll
        for (int n = 0; n < 16; ++n) {
          acc[n][0] *= scalef[0]; acc[n][1] *= scalef[1];
          acc[n][2] *= scalef[2]; acc[n][3] *= scalef[3];
        }
        // P (C-layout) -> per-wave LDS -> A-layout fragments
        bf16* pw = Ps + w * 1152;
#pragma unroll
        for (int n = 0; n < 4; ++n)
#pragma unroll
          for (int i = 0; i < 4; ++i)
            pw[(lq * 4 + i) * 72 + n * 16 + la] = (bf16)s[n][i];
        __builtin_amdgcn_s_setprio(1);
#pragma unroll
        for (int kc = 0; kc < 2; ++kc) {
          bf16x8 pa = *(const bf16x8*)(pw + la * 72 + kc * 32 + lq * 8);
#pragma unroll
          for (int n = 0; n < 16; ++n) {
            int rd = n * 16 + la;
            int sl = (kc * 4 + lq) ^ (rd & 7);
            bf16x8 vbv = *(const bf16x8*)(Vc + rd * 64 + sl * 8);
            acc[n] = __builtin_amdgcn_mfma_f32_16x16x32_bf16(pa, vbv, acc[n], 0, 0, 0);
          }
        }
        __builtin_amdgcn_s_setprio(0);
      }
      __builtin_amdgcn_s_barrier();
      __builtin_amdgcn_sched_barrier(0);
      cur ^= 1;
    }
#pragma unroll
    for (int i = 0; i < 4; ++i) {
      const int row = rbase + lq * 4 + i;
      const float inv = 1.0f / lrow[i];
      bf16* orow = o + ((size_t)(b * 2048 + row)) * 4096 + h * 256;
#pragma unroll
      for (int n = 0; n < 16; ++n) orow[n * 16 + la] = (bf16)(acc[n][i] * inv);
    }
  }
#undef STAGE
}

// ---------------- diagnostic fill if ws too small ----------------
__global__ void fill_err(float* o, int n) {
  int i = blockIdx.x * 256 + threadIdx.x;
  if (i < n) o[i] = 1e9f;
}

extern "C" void kernel_launch(void* const* d_in, const int* in_sizes, int n_in,
                              void* d_out, int out_size, void* d_ws, size_t ws_size,
                              hipStream_t stream) {
  const float* x = (const float*)d_in[0];
  const float* Wq = (const float*)d_in[1];
  const float* Wk = (const float*)d_in[2];
  const float* Wv = (const float*)d_in[3];
  const float* Wo = (const float*)d_in[4];
  const float* kscale = (const float*)d_in[5];
  const float* vscale = (const float*)d_in[6];
  const int* pos = (const int*)d_in[8];
  float* out = (float*)d_out;

  const size_t WS_NEED = 251658240ull;  // 240 MB
  if (ws_size < WS_NEED) {
    fill_err<<<65536, 256, 0, stream>>>(out, out_size);
    return;
  }
  char* ws = (char*)d_ws;
  bf16* x16 = (bf16*)(ws);
  bf16* wqt = (bf16*)(ws + 33554432);
  bf16* wkt = (bf16*)(ws + 67108864);
  bf16* wvt = (bf16*)(ws + 83886080);
  bf16* wot = (bf16*)(ws + 100663296);
  bf16* qb = (bf16*)(ws + 134217728);
  bf16* kb = (bf16*)(ws + 167772160);
  bf16* vb = (bf16*)(ws + 184549376);
  bf16* vtb = (bf16*)(ws + 201326592);
  bf16* ao = (bf16*)(ws + 218103808);

  // prep: bf16 conversions + weight transposes
  cvt_bf16<<<16384, 256, 0, stream>>>(x, x16, 4194304);
  tconv<<<dim3(64, 64), 256, 0, stream>>>(Wq, wqt, 4096, 4096);
  tconv<<<dim3(32, 64), 256, 0, stream>>>(Wk, wkt, 4096, 2048);
  tconv<<<dim3(32, 64), 256, 0, stream>>>(Wv, wvt, 4096, 2048);
  tconv<<<dim3(64, 64), 256, 0, stream>>>(Wo, wot, 4096, 4096);

  // QKV projections
  gemm_bt<0><<<dim3(32, 32), 256, 0, stream>>>(x16, wqt, qb, 4096, 4096, 4096);
  gemm_bt<0><<<dim3(16, 32), 256, 0, stream>>>(x16, wkt, kb, 4096, 2048, 4096);
  gemm_bt<0><<<dim3(16, 32), 256, 0, stream>>>(x16, wvt, vb, 4096, 2048, 4096);

  // norms + rope (q pre-scaled by 1/sqrt(HD))
  rope_q<<<16384, 256, 0, stream>>>(qb, pos);
  norm_rope_k<<<8192, 256, 0, stream>>>(kb, kscale, pos);
  norm_v<<<8192, 256, 0, stream>>>(vb, vscale);
  vtrans<<<dim3(32, 4, 16), 256, 0, stream>>>(vb, vtb);

  // attention: paired-qb load-balanced grid (256 blocks = 1/CU)
  flash_attn<<<dim3(16, 8, 2), 512, 0, stream>>>(qb, kb, vtb, ao);

  // output projection (fp32 out)
  gemm_bt<1><<<dim3(32, 32), 256, 0, stream>>>(ao, wot, out, 4096, 4096, 4096);
}

// Round 4
// 666.731 us; speedup vs baseline: 1.9004x; 1.1160x over previous
//
#include <hip/hip_runtime.h>
#include <stdint.h>

typedef __bf16 bf16;
typedef __bf16 bf16x4 __attribute__((ext_vector_type(4)));
typedef __bf16 bf16x8 __attribute__((ext_vector_type(8)));
typedef float f32x4 __attribute__((ext_vector_type(4)));

#define GAS __attribute__((address_space(1)))
#define LAS __attribute__((address_space(3)))

__device__ __forceinline__ void gload_lds16(const void* g, void* l) {
  __builtin_amdgcn_global_load_lds((GAS const void*)g, (LAS void*)l, 16, 0, 0);
}

// ---------------- fp32 -> bf16 convert (x) ----------------
__global__ __launch_bounds__(256) void cvt_bf16(const float* __restrict__ in,
                                                bf16* __restrict__ out, int n4) {
  int i = blockIdx.x * 256 + threadIdx.x;
  if (i >= n4) return;
  float4 v = ((const float4*)in)[i];
  bf16x4 o;
  o[0] = (bf16)v.x; o[1] = (bf16)v.y; o[2] = (bf16)v.z; o[3] = (bf16)v.w;
  ((bf16x4*)out)[i] = o;
}

// ------------- W[K][N] f32 -> Wt[N][K] bf16 (transpose+convert) -------------
__global__ __launch_bounds__(256) void tconv(const float* __restrict__ W,
                                             bf16* __restrict__ Wt, int K, int N) {
  __shared__ bf16 tile[64][65];
  const int tx = threadIdx.x & 63, ty = threadIdx.x >> 6;
  const int n0 = blockIdx.x * 64, k0 = blockIdx.y * 64;
#pragma unroll
  for (int i = 0; i < 16; ++i) {
    int kr = ty + i * 4;
    tile[kr][tx] = (bf16)W[(size_t)(k0 + kr) * N + n0 + tx];
  }
  __syncthreads();
#pragma unroll
  for (int i = 0; i < 16; ++i) {
    int nr = ty + i * 4;
    Wt[(size_t)(n0 + nr) * K + k0 + tx] = tile[tx][nr];
  }
}

// ============ 256x256 deep-pipelined bf16 GEMM: C = A[M][K] @ Bt[N][K]^T ============
// BK=64, 8 waves (2x4), wave tile 128x64 (8x4 frags of 16x16), K-tile = 4 phases
// (kh-half x m-group). LDS: 2 buf x 4 slabs[256 rows][32 cols] = 128 KB.
// Slot swizzle: phys slot sp = kl ^ ((row>>1)&3)  (inverse applied on staging src,
// forward on ds_read -> 2-way banks = free). Counted vmcnt(4) at kh boundaries only.
template <int OUTF32>
__global__ __launch_bounds__(512, 2) void gemm256(const bf16* __restrict__ A,
                                                  const bf16* __restrict__ Bt,
                                                  void* __restrict__ Cp,
                                                  const int N, const int K,
                                                  const int NBX) {
  __shared__ __attribute__((aligned(16))) bf16 lds[2][4][8192];
  const int t = threadIdx.x, w = t >> 6, l = t & 63;
  const int la = l & 15, lq = l >> 4;
  // bijective XCD swizzle (grid % 8 == 0 for all our launches)
  const int nwg = gridDim.x, cpx = nwg >> 3;
  const int sid = (blockIdx.x & 7) * cpx + (blockIdx.x >> 3);
  const int by = sid / NBX, bx = sid % NBX;
  const int m0 = by * 256, n0 = bx * 256;
  const int wr = w >> 2, wc = w & 3;
  // staging: chunk c (0..511 per instr-round): row=c>>2, phys slot=c&3,
  // logical k-slot = (c&3) ^ ((c>>3)&3); src = row*K + ktile*64 + kh*32 + kl*8
  const int c0 = w * 64 + l;
  const int sr0 = c0 >> 2, soff = (((c0 & 3) ^ ((c0 >> 3) & 3)) << 3);
  const bf16* pA0 = A + (size_t)(m0 + sr0) * K + soff;
  const bf16* pA1 = pA0 + (size_t)128 * K;
  const bf16* pB0 = Bt + (size_t)(n0 + sr0) * K + soff;
  const bf16* pB1 = pB0 + (size_t)128 * K;
  // read slot offset (elements): sp = lq ^ ((row>>1)&3) = lq ^ ((la>>1)&3)
  const int rsl = (lq ^ ((la >> 1) & 3)) << 3;

  f32x4 acc[8][4] = {};

#define STAGE_SLAB(s, nb, kti)                                                \
  do {                                                                        \
    const bf16* p0_ = ((s) & 1) ? pB0 : pA0;                                  \
    const bf16* p1_ = ((s) & 1) ? pB1 : pA1;                                  \
    const size_t ko_ = (size_t)(kti) * 64 + ((s) >> 1) * 32;                  \
    gload_lds16(p0_ + ko_, &lds[nb][s][w * 512]);                             \
    gload_lds16(p1_ + ko_, &lds[nb][s][4096 + w * 512]);                      \
  } while (0)

#define PHASE(kh, mg, LOADB)                                                  \
  {                                                                           \
    bf16x8 a_[4];                                                             \
    _Pragma("unroll") for (int m_ = 0; m_ < 4; ++m_)                          \
        a_[m_] = *(const bf16x8*)&lds[bi][(kh)*2][(wr * 128 + (mg)*64 + m_ * 16 + la) * 32 + rsl]; \
    if (LOADB) {                                                              \
      _Pragma("unroll") for (int n_ = 0; n_ < 4; ++n_)                        \
          bfr[n_] = *(const bf16x8*)&lds[bi][(kh)*2 + 1][(wc * 64 + n_ * 16 + la) * 32 + rsl]; \
    }                                                                         \
    __builtin_amdgcn_s_setprio(1);                                            \
    _Pragma("unroll") for (int m_ = 0; m_ < 4; ++m_)                          \
      _Pragma("unroll") for (int n_ = 0; n_ < 4; ++n_)                        \
          acc[(mg)*4 + m_][n_] = __builtin_amdgcn_mfma_f32_16x16x32_bf16(     \
              a_[m_], bfr[n_], acc[(mg)*4 + m_][n_], 0, 0, 0);                \
    __builtin_amdgcn_s_setprio(0);                                            \
  }

  // prologue: stage all 4 slabs of K-tile 0 into buf 0
  STAGE_SLAB(0, 0, 0);
  STAGE_SLAB(1, 0, 0);
  STAGE_SLAB(2, 0, 0);
  STAGE_SLAB(3, 0, 0);

  const int NT = K >> 6;
  for (int kt = 0; kt < NT; ++kt) {
    const int bi = kt & 1, nbi = bi ^ 1;
    const bool pf = (kt + 1) < NT;
    bf16x8 bfr[4];
    // ---- kh=0 boundary: A0,B0 of this tile must have landed ----
    if (pf) asm volatile("s_waitcnt vmcnt(4)" ::: "memory");
    else    asm volatile("s_waitcnt vmcnt(0)" ::: "memory");
    __builtin_amdgcn_s_barrier();
    __builtin_amdgcn_sched_barrier(0);
    if (pf) STAGE_SLAB(0, nbi, kt + 1);
    PHASE(0, 0, 1)
    __builtin_amdgcn_s_barrier();
    __builtin_amdgcn_sched_barrier(0);
    if (pf) STAGE_SLAB(1, nbi, kt + 1);
    PHASE(0, 1, 0)
    __builtin_amdgcn_s_barrier();
    __builtin_amdgcn_sched_barrier(0);
    // ---- kh=1 boundary: A1,B1 of this tile must have landed ----
    if (pf) asm volatile("s_waitcnt vmcnt(4)" ::: "memory");
    else    asm volatile("s_waitcnt vmcnt(0)" ::: "memory");
    __builtin_amdgcn_s_barrier();
    __builtin_amdgcn_sched_barrier(0);
    if (pf) STAGE_SLAB(2, nbi, kt + 1);
    PHASE(1, 0, 1)
    __builtin_amdgcn_s_barrier();
    __builtin_amdgcn_sched_barrier(0);
    if (pf) STAGE_SLAB(3, nbi, kt + 1);
    PHASE(1, 1, 0)
    __builtin_amdgcn_s_barrier();
    __builtin_amdgcn_sched_barrier(0);
  }
#undef PHASE
#undef STAGE_SLAB

  const int crow = m0 + wr * 128, ccol = n0 + wc * 64;
  if (OUTF32) {
    float* C = (float*)Cp;
#pragma unroll
    for (int mi = 0; mi < 8; ++mi)
#pragma unroll
      for (int ni = 0; ni < 4; ++ni)
#pragma unroll
        for (int i = 0; i < 4; ++i)
          C[(size_t)(crow + mi * 16 + lq * 4 + i) * N + ccol + ni * 16 + la] = acc[mi][ni][i];
  } else {
    bf16* C = (bf16*)Cp;
#pragma unroll
    for (int mi = 0; mi < 8; ++mi)
#pragma unroll
      for (int ni = 0; ni < 4; ++ni)
#pragma unroll
        for (int i = 0; i < 4; ++i)
          C[(size_t)(crow + mi * 16 + lq * 4 + i) * N + ccol + ni * 16 + la] = (bf16)acc[mi][ni][i];
  }
}

// ------- RoPE on q (in fused qkv, row stride 8192; folds 1/sqrt(HD)) -------
__global__ __launch_bounds__(256) void rope_q(bf16* __restrict__ qkv, const int* __restrict__ pos) {
  const int w = threadIdx.x >> 6, l = threadIdx.x & 63;
  const int idx = blockIdx.x * 4 + w;
  const int bt = idx >> 4, h = idx & 15;  // HQ=16
  bf16* p = qkv + (size_t)bt * 8192 + h * 256 + l * 4;
  bf16x4 xv = *(const bf16x4*)p;
  float x[4], y[4];
#pragma unroll
  for (int j = 0; j < 4; ++j) x[j] = (float)xv[j];
#pragma unroll
  for (int j = 0; j < 4; ++j) y[j] = __shfl_xor(x[j], 32, 64);
  const float posf = (float)pos[bt];
  bf16x4 ov;
#pragma unroll
  for (int j = 0; j < 4; ++j) {
    const int pr = (l & 31) * 4 + j;  // pair index 0..127
    float sv, cv;
    sincosf(posf * exp2f((float)pr * (-13.287712379549449f / 128.0f)), &sv, &cv);
    float o = x[j] * cv + ((l < 32) ? -y[j] : y[j]) * sv;
    ov[j] = (bf16)(o * 0.0625f);  // 1/sqrt(256), exact pow2
  }
  *(bf16x4*)p = ov;
}

// ------- RMSNorm + RoPE on k (fused qkv +4096, row stride 8192) -------
__global__ __launch_bounds__(256) void norm_rope_k(bf16* __restrict__ kbase,
                                                   const float* __restrict__ scale,
                                                   const int* __restrict__ pos) {
  const int w = threadIdx.x >> 6, l = threadIdx.x & 63;
  const int idx = blockIdx.x * 4 + w;
  const int bt = idx >> 3, h = idx & 7;  // HKV=8
  bf16* p = kbase + (size_t)bt * 8192 + h * 256 + l * 4;
  bf16x4 xv = *(const bf16x4*)p;
  float x[4];
#pragma unroll
  for (int j = 0; j < 4; ++j) x[j] = (float)xv[j];
  float ss = x[0] * x[0] + x[1] * x[1] + x[2] * x[2] + x[3] * x[3];
#pragma unroll
  for (int m = 1; m < 64; m <<= 1) ss += __shfl_xor(ss, m, 64);
  const float r = rsqrtf(ss * (1.0f / 256.0f) + 1e-6f);
#pragma unroll
  for (int j = 0; j < 4; ++j) x[j] = x[j] * r * (1.0f + scale[l * 4 + j]);
  float y[4];
#pragma unroll
  for (int j = 0; j < 4; ++j) y[j] = __shfl_xor(x[j], 32, 64);
  const float posf = (float)pos[bt];
  bf16x4 ov;
#pragma unroll
  for (int j = 0; j < 4; ++j) {
    const int pr = (l & 31) * 4 + j;
    float sv, cv;
    sincosf(posf * exp2f((float)pr * (-13.287712379549449f / 128.0f)), &sv, &cv);
    float o = x[j] * cv + ((l < 32) ? -y[j] : y[j]) * sv;
    ov[j] = (bf16)o;
  }
  *(bf16x4*)p = ov;
}

// ------- RMSNorm on v (fused qkv +6144, row stride 8192) -------
__global__ __launch_bounds__(256) void norm_v(bf16* __restrict__ vbase,
                                              const float* __restrict__ scale) {
  const int w = threadIdx.x >> 6, l = threadIdx.x & 63;
  const int idx = blockIdx.x * 4 + w;
  const int bt = idx >> 3, h = idx & 7;
  bf16* p = vbase + (size_t)bt * 8192 + h * 256 + l * 4;
  bf16x4 xv = *(const bf16x4*)p;
  float x[4];
#pragma unroll
  for (int j = 0; j < 4; ++j) x[j] = (float)xv[j];
  float ss = x[0] * x[0] + x[1] * x[1] + x[2] * x[2] + x[3] * x[3];
#pragma unroll
  for (int m = 1; m < 64; m <<= 1) ss += __shfl_xor(ss, m, 64);
  const float r = rsqrtf(ss * (1.0f / 256.0f) + 1e-6f);
  bf16x4 ov;
#pragma unroll
  for (int j = 0; j < 4; ++j) ov[j] = (bf16)(x[j] * r * (1.0f + scale[l * 4 + j]));
  *(bf16x4*)p = ov;
}

// -------- v (in fused qkv) -> vt [b,hkv,d,t] (tiled transpose, bf16) --------
__global__ __launch_bounds__(256) void vtrans(const bf16* __restrict__ vbase,
                                              bf16* __restrict__ vt) {
  __shared__ bf16 tile[64][65];
  const int tx = threadIdx.x & 63, ty = threadIdx.x >> 6;
  const int tt = blockIdx.x, dd = blockIdx.y, bh = blockIdx.z;
  const int b = bh >> 3, h = bh & 7;
#pragma unroll
  for (int i = 0; i < 16; ++i) {
    int trow = tt * 64 + ty + i * 4;
    tile[ty + i * 4][tx] = vbase[(size_t)(b * 2048 + trow) * 8192 + h * 256 + dd * 64 + tx];
  }
  __syncthreads();
#pragma unroll
  for (int i = 0; i < 16; ++i) {
    int drow = dd * 64 + ty + i * 4;
    vt[((size_t)(b * 8 + h) * 256 + drow) * 2048 + tt * 64 + tx] = tile[tx][ty + i * 4];
  }
}

// ---------------- flash attention (causal, GQA group=2) ----------------
// block = (h, qbp, b): processes qb pair {15-qbp, qbp} (34 K/V tiles each,
// 256 blocks = 1/CU). K read from fused qkv (row stride 8192).
__global__ __launch_bounds__(512, 2) void flash_attn(const bf16* __restrict__ qkv,
                                                     const bf16* __restrict__ vt,
                                                     bf16* __restrict__ o) {
  __shared__ __attribute__((aligned(16))) bf16 Ks[2 * 16384];
  __shared__ __attribute__((aligned(16))) bf16 Vs[2 * 16384];
  __shared__ __attribute__((aligned(16))) bf16 Ps[8 * 1152];  // per-wave [16][72]
  const int t = threadIdx.x, w = t >> 6, l = t & 63;
  const int la = l & 15, lq = l >> 4;
  const int h = blockIdx.x, qbp = blockIdx.y, b = blockIdx.z;
  const int hkv = h >> 1;

  const bf16* kbase = qkv + (size_t)(b * 2048) * 8192 + 4096 + hkv * 256;
  const bf16* vbase = vt + ((size_t)(b * 8 + hkv)) * 256 * 2048;

  // staging: K chunk c=i*512+t -> row=c>>5, slot=c&31, src slot^(row&7)
  //          V chunk c        -> row=c>>3, slot=c&7,  src slot^(row&7)
  const bf16* ksrc[4];
  const bf16* vsrc[4];
#pragma unroll
  for (int i = 0; i < 4; ++i) {
    int c = i * 512 + t;
    int krr = c >> 5, ksl = (c & 31) ^ (krr & 7);
    int vrr = c >> 3, vsl = (c & 7) ^ (vrr & 7);
    ksrc[i] = kbase + (size_t)krr * 8192 + ksl * 8;
    vsrc[i] = vbase + (size_t)vrr * 2048 + vsl * 8;
  }

#define STAGE(bb, tt0)                                                        \
  do {                                                                        \
    _Pragma("unroll") for (int i_ = 0; i_ < 4; ++i_)                          \
        gload_lds16(ksrc[i_] + (size_t)(tt0) * 8192,                          \
                    Ks + (bb) * 16384 + i_ * 4096 + w * 512);                 \
    _Pragma("unroll") for (int i_ = 0; i_ < 4; ++i_)                          \
        gload_lds16(vsrc[i_] + (tt0), Vs + (bb) * 16384 + i_ * 4096 + w * 512); \
  } while (0)

  for (int part = 0; part < 2; ++part) {
    const int qb = part ? qbp : (15 - qbp);
    const int q0 = qb * 128;
    const int rbase = q0 + w * 16;

    bf16x8 qf[8];
    {
      const bf16* qrow = qkv + (size_t)(b * 2048 + rbase + la) * 8192 + h * 256 + lq * 8;
#pragma unroll
      for (int kg = 0; kg < 8; ++kg) qf[kg] = *(const bf16x8*)(qrow + kg * 32);
    }
    f32x4 acc[16] = {};
    float mrow[4] = {-1e30f, -1e30f, -1e30f, -1e30f};
    float lrow[4] = {0.f, 0.f, 0.f, 0.f};
    const int nT = 2 * qb + 2;

    STAGE(0, 0);
    int cur = 0;
    for (int tti = 0; tti < nT; ++tti) {
      const int t0 = tti * 64;
      if (tti + 1 < nT) {
        STAGE(cur ^ 1, t0 + 64);
        asm volatile("s_waitcnt vmcnt(8)" ::: "memory");  // cur landed, next flies
      } else {
        asm volatile("s_waitcnt vmcnt(0)" ::: "memory");
      }
      __builtin_amdgcn_s_barrier();
      __builtin_amdgcn_sched_barrier(0);
      if (t0 <= rbase + 15) {
        const bf16* Kc = Ks + cur * 16384;
        const bf16* Vc = Vs + cur * 16384;
        f32x4 s[4] = {};
        __builtin_amdgcn_s_setprio(1);
#pragma unroll
        for (int n = 0; n < 4; ++n) {
          int rT = n * 16 + la;
#pragma unroll
          for (int kg = 0; kg < 8; ++kg) {
            int sl = (kg * 4 + lq) ^ (rT & 7);
            bf16x8 kbv = *(const bf16x8*)(Kc + rT * 256 + sl * 8);
            s[n] = __builtin_amdgcn_mfma_f32_16x16x32_bf16(qf[kg], kbv, s[n], 0, 0, 0);
          }
        }
        __builtin_amdgcn_s_setprio(0);
        float scalef[4];
#pragma unroll
        for (int i = 0; i < 4; ++i) {
          const int row = rbase + lq * 4 + i;
          float mx = -1e30f;
#pragma unroll
          for (int n = 0; n < 4; ++n) {
            float v = s[n][i];
            v = (t0 + n * 16 + la > row) ? -1e30f : v;
            s[n][i] = v;
            mx = fmaxf(mx, v);
          }
          mx = fmaxf(mx, __shfl_xor(mx, 1, 64));
          mx = fmaxf(mx, __shfl_xor(mx, 2, 64));
          mx = fmaxf(mx, __shfl_xor(mx, 4, 64));
          mx = fmaxf(mx, __shfl_xor(mx, 8, 64));
          const float mnew = fmaxf(mrow[i], mx);
          scalef[i] = __expf(mrow[i] - mnew);
          float ps = 0.f;
#pragma unroll
          for (int n = 0; n < 4; ++n) {
            float v = s[n][i];
            float pp = (v <= -1e29f) ? 0.f : __expf(v - mnew);
            s[n][i] = pp;
            ps += pp;
          }
          ps += __shfl_xor(ps, 1, 64);
          ps += __shfl_xor(ps, 2, 64);
          ps += __shfl_xor(ps, 4, 64);
          ps += __shfl_xor(ps, 8, 64);
          mrow[i] = mnew;
          lrow[i] = lrow[i] * scalef[i] + ps;
        }
#pragma unroll
        for (int n = 0; n < 16; ++n) {
          acc[n][0] *= scalef[0]; acc[n][1] *= scalef[1];
          acc[n][2] *= scalef[2]; acc[n][3] *= scalef[3];
        }
        bf16* pw = Ps + w * 1152;
#pragma unroll
        for (int n = 0; n < 4; ++n)
#pragma unroll
          for (int i = 0; i < 4; ++i)
            pw[(lq * 4 + i) * 72 + n * 16 + la] = (bf16)s[n][i];
        __builtin_amdgcn_s_setprio(1);
#pragma unroll
        for (int kc = 0; kc < 2; ++kc) {
          bf16x8 pa = *(const bf16x8*)(pw + la * 72 + kc * 32 + lq * 8);
#pragma unroll
          for (int n = 0; n < 16; ++n) {
            int rd = n * 16 + la;
            int sl = (kc * 4 + lq) ^ (rd & 7);
            bf16x8 vbv = *(const bf16x8*)(Vc + rd * 64 + sl * 8);
            acc[n] = __builtin_amdgcn_mfma_f32_16x16x32_bf16(pa, vbv, acc[n], 0, 0, 0);
          }
        }
        __builtin_amdgcn_s_setprio(0);
      }
      __builtin_amdgcn_s_barrier();
      __builtin_amdgcn_sched_barrier(0);
      cur ^= 1;
    }
#pragma unroll
    for (int i = 0; i < 4; ++i) {
      const int row = rbase + lq * 4 + i;
      const float inv = 1.0f / lrow[i];
      bf16* orow = o + ((size_t)(b * 2048 + row)) * 4096 + h * 256;
#pragma unroll
      for (int n = 0; n < 16; ++n) orow[n * 16 + la] = (bf16)(acc[n][i] * inv);
    }
  }
#undef STAGE
}

// ---------------- diagnostic fill if ws too small ----------------
__global__ void fill_err(float* o, int n) {
  int i = blockIdx.x * 256 + threadIdx.x;
  if (i < n) o[i] = 1e9f;
}

extern "C" void kernel_launch(void* const* d_in, const int* in_sizes, int n_in,
                              void* d_out, int out_size, void* d_ws, size_t ws_size,
                              hipStream_t stream) {
  const float* x = (const float*)d_in[0];
  const float* Wq = (const float*)d_in[1];
  const float* Wk = (const float*)d_in[2];
  const float* Wv = (const float*)d_in[3];
  const float* Wo = (const float*)d_in[4];
  const float* kscale = (const float*)d_in[5];
  const float* vscale = (const float*)d_in[6];
  const int* pos = (const int*)d_in[8];
  float* out = (float*)d_out;

  const size_t WS_NEED = 251658240ull;  // 240 MB
  if (ws_size < WS_NEED) {
    fill_err<<<65536, 256, 0, stream>>>(out, out_size);
    return;
  }
  char* ws = (char*)d_ws;
  bf16* x16   = (bf16*)(ws);                  // [4096][4096]   32 MB
  bf16* wqkvt = (bf16*)(ws + 33554432);       // [8192][4096]   64 MB (Q|K|V rows)
  bf16* wot   = (bf16*)(ws + 100663296);      // [4096][4096]   32 MB
  bf16* qkv   = (bf16*)(ws + 134217728);      // [4096][8192]   64 MB (Q|K|V cols)
  bf16* vtb   = (bf16*)(ws + 201326592);      // [2][8][256][2048] 16 MB
  bf16* ao    = (bf16*)(ws + 218103808);      // [4096][4096]   32 MB

  // prep: bf16 conversions + weight transposes (concatenated along N)
  cvt_bf16<<<16384, 256, 0, stream>>>(x, x16, 4194304);
  tconv<<<dim3(64, 64), 256, 0, stream>>>(Wq, wqkvt, 4096, 4096);
  tconv<<<dim3(32, 64), 256, 0, stream>>>(Wk, wqkvt + (size_t)4096 * 4096, 4096, 2048);
  tconv<<<dim3(32, 64), 256, 0, stream>>>(Wv, wqkvt + (size_t)6144 * 4096, 4096, 2048);
  tconv<<<dim3(64, 64), 256, 0, stream>>>(Wo, wot, 4096, 4096);

  // fused QKV projection: [4096][8192] = x16 @ wqkvt^T
  gemm256<0><<<512, 512, 0, stream>>>(x16, wqkvt, qkv, 8192, 4096, 32);

  // norms + rope on fused layout (q pre-scaled by 1/sqrt(HD))
  rope_q<<<16384, 256, 0, stream>>>(qkv, pos);
  norm_rope_k<<<8192, 256, 0, stream>>>(qkv + 4096, kscale, pos);
  norm_v<<<8192, 256, 0, stream>>>(qkv + 6144, vscale);
  vtrans<<<dim3(32, 4, 16), 256, 0, stream>>>(qkv + 6144, vtb);

  // attention: paired-qb load-balanced grid (256 blocks = 1/CU)
  flash_attn<<<dim3(16, 8, 2), 512, 0, stream>>>(qkv, vtb, ao);

  // output projection (fp32 out)
  gemm256<1><<<256, 512, 0, stream>>>(ao, wot, out, 4096, 4096, 16);
}

// Round 5
// 634.358 us; speedup vs baseline: 1.9974x; 1.0510x over previous
//
#include <hip/hip_runtime.h>
#include <stdint.h>

typedef __bf16 bf16;
typedef __bf16 bf16x4 __attribute__((ext_vector_type(4)));
typedef __bf16 bf16x8 __attribute__((ext_vector_type(8)));
typedef float f32x4 __attribute__((ext_vector_type(4)));

#define GAS __attribute__((address_space(1)))
#define LAS __attribute__((address_space(3)))

__device__ __forceinline__ void gload_lds16(const void* g, void* l) {
  __builtin_amdgcn_global_load_lds((GAS const void*)g, (LAS void*)l, 16, 0, 0);
}

// ---------------- fp32 -> bf16 convert (x) ----------------
__global__ __launch_bounds__(256) void cvt_bf16(const float* __restrict__ in,
                                                bf16* __restrict__ out, int n4) {
  int i = blockIdx.x * 256 + threadIdx.x;
  if (i >= n4) return;
  float4 v = ((const float4*)in)[i];
  bf16x4 o;
  o[0] = (bf16)v.x; o[1] = (bf16)v.y; o[2] = (bf16)v.z; o[3] = (bf16)v.w;
  ((bf16x4*)out)[i] = o;
}

// ------------- W[K][N] f32 -> Wt[N][K] bf16 (transpose+convert) -------------
__global__ __launch_bounds__(256) void tconv(const float* __restrict__ W,
                                             bf16* __restrict__ Wt, int K, int N) {
  __shared__ bf16 tile[64][65];
  const int tx = threadIdx.x & 63, ty = threadIdx.x >> 6;
  const int n0 = blockIdx.x * 64, k0 = blockIdx.y * 64;
#pragma unroll
  for (int i = 0; i < 16; ++i) {
    int kr = ty + i * 4;
    tile[kr][tx] = (bf16)W[(size_t)(k0 + kr) * N + n0 + tx];
  }
  __syncthreads();
#pragma unroll
  for (int i = 0; i < 16; ++i) {
    int nr = ty + i * 4;
    Wt[(size_t)(n0 + nr) * K + k0 + tx] = tile[tx][nr];
  }
}

// ============ 256x256 deep-pipelined bf16 GEMM: C = A[M][K] @ Bt[N][K]^T ============
// BK=64, 8 waves (2x4), wave tile 128x64 (8x4 frags of 16x16). LDS: 2 buf x 4
// slabs[256 rows][32 cols] = 128 KB, slot swizzle sp = kl ^ ((row>>1)&3)
// (inverse on staging src, forward on ds_read -> 2-way banks = free).
// Sync: 2 barriers per K-tile (one per kh boundary) + counted vmcnt(4) - slabs
// of tile t+1 stay in flight across barriers. 2D XCD chunking: each XCD owns an
// (8 by) x (2^cbx_l bx) chunk so A/B panels are L2-resident per XCD.
template <int OUTF32>
__global__ __launch_bounds__(512, 2) void gemm256(const bf16* __restrict__ A,
                                                  const bf16* __restrict__ Bt,
                                                  void* __restrict__ Cp,
                                                  const int N, const int K,
                                                  const int ncc_l, const int cbx_l) {
  __shared__ __attribute__((aligned(16))) bf16 lds[2][4][8192];
  const int t = threadIdx.x, w = t >> 6, l = t & 63;
  const int la = l & 15, lq = l >> 4;
  // 2D XCD chunk map: consecutive blockIdx round-robin across XCDs
  const int xcd = blockIdx.x & 7, wi = blockIdx.x >> 3;
  const int cr = xcd >> ncc_l, cc = xcd & ((1 << ncc_l) - 1);
  const int by = (cr << 3) + (wi >> cbx_l);
  const int bx = (cc << cbx_l) + (wi & ((1 << cbx_l) - 1));
  const int m0 = by * 256, n0 = bx * 256;
  const int wr = w >> 2, wc = w & 3;
  // staging: chunk c (0..511): row=c>>2, phys slot=c&3,
  // logical k-slot = (c&3) ^ ((c>>3)&3); src = row*K + ktile*64 + kh*32 + kl*8
  const int c0 = w * 64 + l;
  const int sr0 = c0 >> 2, soff = (((c0 & 3) ^ ((c0 >> 3) & 3)) << 3);
  const bf16* pA0 = A + (size_t)(m0 + sr0) * K + soff;
  const bf16* pA1 = pA0 + (size_t)128 * K;
  const bf16* pB0 = Bt + (size_t)(n0 + sr0) * K + soff;
  const bf16* pB1 = pB0 + (size_t)128 * K;
  // read slot offset (elements): sp = lq ^ ((row>>1)&3) = lq ^ ((la>>1)&3)
  const int rsl = (lq ^ ((la >> 1) & 3)) << 3;

  f32x4 acc[8][4] = {};

#define STAGE_SLAB(s, nb, kti)                                                \
  do {                                                                        \
    const bf16* p0_ = ((s) & 1) ? pB0 : pA0;                                  \
    const bf16* p1_ = ((s) & 1) ? pB1 : pA1;                                  \
    const size_t ko_ = (size_t)(kti) * 64 + ((s) >> 1) * 32;                  \
    gload_lds16(p0_ + ko_, &lds[nb][s][w * 512]);                             \
    gload_lds16(p1_ + ko_, &lds[nb][s][4096 + w * 512]);                      \
  } while (0)

#define PHASE(kh, mg)                                                         \
  {                                                                           \
    bf16x8 a_[4];                                                             \
    _Pragma("unroll") for (int m_ = 0; m_ < 4; ++m_)                          \
        a_[m_] = *(const bf16x8*)&lds[bi][(kh)*2][(wr * 128 + (mg)*64 + m_ * 16 + la) * 32 + rsl]; \
    __builtin_amdgcn_s_setprio(1);                                            \
    _Pragma("unroll") for (int m_ = 0; m_ < 4; ++m_)                          \
      _Pragma("unroll") for (int n_ = 0; n_ < 4; ++n_)                        \
          acc[(mg)*4 + m_][n_] = __builtin_amdgcn_mfma_f32_16x16x32_bf16(     \
              a_[m_], bfr[n_], acc[(mg)*4 + m_][n_], 0, 0, 0);                \
    __builtin_amdgcn_s_setprio(0);                                            \
  }

  // prologue: stage all 4 slabs of K-tile 0 into buf 0
  STAGE_SLAB(0, 0, 0);
  STAGE_SLAB(1, 0, 0);
  STAGE_SLAB(2, 0, 0);
  STAGE_SLAB(3, 0, 0);

  const int NT = K >> 6;
  for (int kt = 0; kt < NT; ++kt) {
    const int bi = kt & 1, nbi = bi ^ 1;
    const bool pf = (kt + 1) < NT;
    bf16x8 bfr[4];
    // ---- kh=0 boundary: slabs 0,1 of this tile must have landed ----
    if (pf) asm volatile("s_waitcnt vmcnt(4)" ::: "memory");
    else    asm volatile("s_waitcnt vmcnt(0)" ::: "memory");
    __builtin_amdgcn_s_barrier();
    __builtin_amdgcn_sched_barrier(0);
    if (pf) STAGE_SLAB(0, nbi, kt + 1);
#pragma unroll
    for (int n_ = 0; n_ < 4; ++n_)
      bfr[n_] = *(const bf16x8*)&lds[bi][1][(wc * 64 + n_ * 16 + la) * 32 + rsl];
    PHASE(0, 0)
    if (pf) STAGE_SLAB(1, nbi, kt + 1);
    PHASE(0, 1)
    // ---- kh=1 boundary: slabs 2,3 of this tile must have landed ----
    if (pf) asm volatile("s_waitcnt vmcnt(4)" ::: "memory");
    else    asm volatile("s_waitcnt vmcnt(0)" ::: "memory");
    __builtin_amdgcn_s_barrier();
    __builtin_amdgcn_sched_barrier(0);
    if (pf) STAGE_SLAB(2, nbi, kt + 1);
#pragma unroll
    for (int n_ = 0; n_ < 4; ++n_)
      bfr[n_] = *(const bf16x8*)&lds[bi][3][(wc * 64 + n_ * 16 + la) * 32 + rsl];
    PHASE(1, 0)
    if (pf) STAGE_SLAB(3, nbi, kt + 1);
    PHASE(1, 1)
  }
#undef PHASE
#undef STAGE_SLAB

  const int crow = m0 + wr * 128, ccol = n0 + wc * 64;
  if (OUTF32) {
    float* C = (float*)Cp;
#pragma unroll
    for (int mi = 0; mi < 8; ++mi)
#pragma unroll
      for (int ni = 0; ni < 4; ++ni)
#pragma unroll
        for (int i = 0; i < 4; ++i)
          C[(size_t)(crow + mi * 16 + lq * 4 + i) * N + ccol + ni * 16 + la] = acc[mi][ni][i];
  } else {
    bf16* C = (bf16*)Cp;
#pragma unroll
    for (int mi = 0; mi < 8; ++mi)
#pragma unroll
      for (int ni = 0; ni < 4; ++ni)
#pragma unroll
        for (int i = 0; i < 4; ++i)
          C[(size_t)(crow + mi * 16 + lq * 4 + i) * N + ccol + ni * 16 + la] = (bf16)acc[mi][ni][i];
  }
}

// ------- RoPE on q (in fused qkv, row stride 8192; folds 1/sqrt(HD)) -------
__global__ __launch_bounds__(256) void rope_q(bf16* __restrict__ qkv, const int* __restrict__ pos) {
  const int w = threadIdx.x >> 6, l = threadIdx.x & 63;
  const int idx = blockIdx.x * 4 + w;
  const int bt = idx >> 4, h = idx & 15;  // HQ=16
  bf16* p = qkv + (size_t)bt * 8192 + h * 256 + l * 4;
  bf16x4 xv = *(const bf16x4*)p;
  float x[4], y[4];
#pragma unroll
  for (int j = 0; j < 4; ++j) x[j] = (float)xv[j];
#pragma unroll
  for (int j = 0; j < 4; ++j) y[j] = __shfl_xor(x[j], 32, 64);
  const float posf = (float)pos[bt];
  bf16x4 ov;
#pragma unroll
  for (int j = 0; j < 4; ++j) {
    const int pr = (l & 31) * 4 + j;  // pair index 0..127
    float sv, cv;
    sincosf(posf * exp2f((float)pr * (-13.287712379549449f / 128.0f)), &sv, &cv);
    float o = x[j] * cv + ((l < 32) ? -y[j] : y[j]) * sv;
    ov[j] = (bf16)(o * 0.0625f);  // 1/sqrt(256), exact pow2
  }
  *(bf16x4*)p = ov;
}

// ------- RMSNorm + RoPE on k (fused qkv +4096, row stride 8192) -------
__global__ __launch_bounds__(256) void norm_rope_k(bf16* __restrict__ kbase,
                                                   const float* __restrict__ scale,
                                                   const int* __restrict__ pos) {
  const int w = threadIdx.x >> 6, l = threadIdx.x & 63;
  const int idx = blockIdx.x * 4 + w;
  const int bt = idx >> 3, h = idx & 7;  // HKV=8
  bf16* p = kbase + (size_t)bt * 8192 + h * 256 + l * 4;
  bf16x4 xv = *(const bf16x4*)p;
  float x[4];
#pragma unroll
  for (int j = 0; j < 4; ++j) x[j] = (float)xv[j];
  float ss = x[0] * x[0] + x[1] * x[1] + x[2] * x[2] + x[3] * x[3];
#pragma unroll
  for (int m = 1; m < 64; m <<= 1) ss += __shfl_xor(ss, m, 64);
  const float r = rsqrtf(ss * (1.0f / 256.0f) + 1e-6f);
#pragma unroll
  for (int j = 0; j < 4; ++j) x[j] = x[j] * r * (1.0f + scale[l * 4 + j]);
  float y[4];
#pragma unroll
  for (int j = 0; j < 4; ++j) y[j] = __shfl_xor(x[j], 32, 64);
  const float posf = (float)pos[bt];
  bf16x4 ov;
#pragma unroll
  for (int j = 0; j < 4; ++j) {
    const int pr = (l & 31) * 4 + j;
    float sv, cv;
    sincosf(posf * exp2f((float)pr * (-13.287712379549449f / 128.0f)), &sv, &cv);
    float o = x[j] * cv + ((l < 32) ? -y[j] : y[j]) * sv;
    ov[j] = (bf16)o;
  }
  *(bf16x4*)p = ov;
}

// ------- RMSNorm on v (fused qkv +6144, row stride 8192) -------
__global__ __launch_bounds__(256) void norm_v(bf16* __restrict__ vbase,
                                              const float* __restrict__ scale) {
  const int w = threadIdx.x >> 6, l = threadIdx.x & 63;
  const int idx = blockIdx.x * 4 + w;
  const int bt = idx >> 3, h = idx & 7;
  bf16* p = vbase + (size_t)bt * 8192 + h * 256 + l * 4;
  bf16x4 xv = *(const bf16x4*)p;
  float x[4];
#pragma unroll
  for (int j = 0; j < 4; ++j) x[j] = (float)xv[j];
  float ss = x[0] * x[0] + x[1] * x[1] + x[2] * x[2] + x[3] * x[3];
#pragma unroll
  for (int m = 1; m < 64; m <<= 1) ss += __shfl_xor(ss, m, 64);
  const float r = rsqrtf(ss * (1.0f / 256.0f) + 1e-6f);
  bf16x4 ov;
#pragma unroll
  for (int j = 0; j < 4; ++j) ov[j] = (bf16)(x[j] * r * (1.0f + scale[l * 4 + j]));
  *(bf16x4*)p = ov;
}

// -------- v (in fused qkv) -> vt [b,hkv,d,t] (tiled transpose, bf16) --------
__global__ __launch_bounds__(256) void vtrans(const bf16* __restrict__ vbase,
                                              bf16* __restrict__ vt) {
  __shared__ bf16 tile[64][65];
  const int tx = threadIdx.x & 63, ty = threadIdx.x >> 6;
  const int tt = blockIdx.x, dd = blockIdx.y, bh = blockIdx.z;
  const int b = bh >> 3, h = bh & 7;
#pragma unroll
  for (int i = 0; i < 16; ++i) {
    int trow = tt * 64 + ty + i * 4;
    tile[ty + i * 4][tx] = vbase[(size_t)(b * 2048 + trow) * 8192 + h * 256 + dd * 64 + tx];
  }
  __syncthreads();
#pragma unroll
  for (int i = 0; i < 16; ++i) {
    int drow = dd * 64 + ty + i * 4;
    vt[((size_t)(b * 8 + h) * 256 + drow) * 2048 + tt * 64 + tx] = tile[tx][ty + i * 4];
  }
}

// ---------------- flash attention (causal, GQA group=2) ----------------
// block = (h, qbp, b): processes qb pair {15-qbp, qbp} (34 K/V tiles each,
// 256 blocks = 1/CU). K read from fused qkv (row stride 8192).
__global__ __launch_bounds__(512, 2) void flash_attn(const bf16* __restrict__ qkv,
                                                     const bf16* __restrict__ vt,
                                                     bf16* __restrict__ o) {
  __shared__ __attribute__((aligned(16))) bf16 Ks[2 * 16384];
  __shared__ __attribute__((aligned(16))) bf16 Vs[2 * 16384];
  __shared__ __attribute__((aligned(16))) bf16 Ps[8 * 1152];  // per-wave [16][72]
  const int t = threadIdx.x, w = t >> 6, l = t & 63;
  const int la = l & 15, lq = l >> 4;
  const int h = blockIdx.x, qbp = blockIdx.y, b = blockIdx.z;
  const int hkv = h >> 1;

  const bf16* kbase = qkv + (size_t)(b * 2048) * 8192 + 4096 + hkv * 256;
  const bf16* vbase = vt + ((size_t)(b * 8 + hkv)) * 256 * 2048;

  // staging: K chunk c=i*512+t -> row=c>>5, slot=c&31, src slot^(row&7)
  //          V chunk c        -> row=c>>3, slot=c&7,  src slot^(row&7)
  const bf16* ksrc[4];
  const bf16* vsrc[4];
#pragma unroll
  for (int i = 0; i < 4; ++i) {
    int c = i * 512 + t;
    int krr = c >> 5, ksl = (c & 31) ^ (krr & 7);
    int vrr = c >> 3, vsl = (c & 7) ^ (vrr & 7);
    ksrc[i] = kbase + (size_t)krr * 8192 + ksl * 8;
    vsrc[i] = vbase + (size_t)vrr * 2048 + vsl * 8;
  }

#define STAGE(bb, tt0)                                                        \
  do {                                                                        \
    _Pragma("unroll") for (int i_ = 0; i_ < 4; ++i_)                          \
        gload_lds16(ksrc[i_] + (size_t)(tt0) * 8192,                          \
                    Ks + (bb) * 16384 + i_ * 4096 + w * 512);                 \
    _Pragma("unroll") for (int i_ = 0; i_ < 4; ++i_)                          \
        gload_lds16(vsrc[i_] + (tt0), Vs + (bb) * 16384 + i_ * 4096 + w * 512); \
  } while (0)

  for (int part = 0; part < 2; ++part) {
    const int qb = part ? qbp : (15 - qbp);
    const int q0 = qb * 128;
    const int rbase = q0 + w * 16;

    bf16x8 qf[8];
    {
      const bf16* qrow = qkv + (size_t)(b * 2048 + rbase + la) * 8192 + h * 256 + lq * 8;
#pragma unroll
      for (int kg = 0; kg < 8; ++kg) qf[kg] = *(const bf16x8*)(qrow + kg * 32);
    }
    f32x4 acc[16] = {};
    float mrow[4] = {-1e30f, -1e30f, -1e30f, -1e30f};
    float lrow[4] = {0.f, 0.f, 0.f, 0.f};
    const int nT = 2 * qb + 2;

    STAGE(0, 0);
    int cur = 0;
    for (int tti = 0; tti < nT; ++tti) {
      const int t0 = tti * 64;
      if (tti + 1 < nT) {
        STAGE(cur ^ 1, t0 + 64);
        asm volatile("s_waitcnt vmcnt(8)" ::: "memory");  // cur landed, next flies
      } else {
        asm volatile("s_waitcnt vmcnt(0)" ::: "memory");
      }
      __builtin_amdgcn_s_barrier();
      __builtin_amdgcn_sched_barrier(0);
      if (t0 <= rbase + 15) {
        const bf16* Kc = Ks + cur * 16384;
        const bf16* Vc = Vs + cur * 16384;
        f32x4 s[4] = {};
        __builtin_amdgcn_s_setprio(1);
#pragma unroll
        for (int n = 0; n < 4; ++n) {
          int rT = n * 16 + la;
#pragma unroll
          for (int kg = 0; kg < 8; ++kg) {
            int sl = (kg * 4 + lq) ^ (rT & 7);
            bf16x8 kbv = *(const bf16x8*)(Kc + rT * 256 + sl * 8);
            s[n] = __builtin_amdgcn_mfma_f32_16x16x32_bf16(qf[kg], kbv, s[n], 0, 0, 0);
          }
        }
        __builtin_amdgcn_s_setprio(0);
        float scalef[4];
#pragma unroll
        for (int i = 0; i < 4; ++i) {
          const int row = rbase + lq * 4 + i;
          float mx = -1e30f;
#pragma unroll
          for (int n = 0; n < 4; ++n) {
            float v = s[n][i];
            v = (t0 + n * 16 + la > row) ? -1e30f : v;
            s[n][i] = v;
            mx = fmaxf(mx, v);
          }
          mx = fmaxf(mx, __shfl_xor(mx, 1, 64));
          mx = fmaxf(mx, __shfl_xor(mx, 2, 64));
          mx = fmaxf(mx, __shfl_xor(mx, 4, 64));
          mx = fmaxf(mx, __shfl_xor(mx, 8, 64));
          const float mnew = fmaxf(mrow[i], mx);
          scalef[i] = __expf(mrow[i] - mnew);
          float ps = 0.f;
#pragma unroll
          for (int n = 0; n < 4; ++n) {
            float v = s[n][i];
            float pp = (v <= -1e29f) ? 0.f : __expf(v - mnew);
            s[n][i] = pp;
            ps += pp;
          }
          ps += __shfl_xor(ps, 1, 64);
          ps += __shfl_xor(ps, 2, 64);
          ps += __shfl_xor(ps, 4, 64);
          ps += __shfl_xor(ps, 8, 64);
          mrow[i] = mnew;
          lrow[i] = lrow[i] * scalef[i] + ps;
        }
#pragma unroll
        for (int n = 0; n < 16; ++n) {
          acc[n][0] *= scalef[0]; acc[n][1] *= scalef[1];
          acc[n][2] *= scalef[2]; acc[n][3] *= scalef[3];
        }
        bf16* pw = Ps + w * 1152;
#pragma unroll
        for (int n = 0; n < 4; ++n)
#pragma unroll
          for (int i = 0; i < 4; ++i)
            pw[(lq * 4 + i) * 72 + n * 16 + la] = (bf16)s[n][i];
        __builtin_amdgcn_s_setprio(1);
#pragma unroll
        for (int kc = 0; kc < 2; ++kc) {
          bf16x8 pa = *(const bf16x8*)(pw + la * 72 + kc * 32 + lq * 8);
#pragma unroll
          for (int n = 0; n < 16; ++n) {
            int rd = n * 16 + la;
            int sl = (kc * 4 + lq) ^ (rd & 7);
            bf16x8 vbv = *(const bf16x8*)(Vc + rd * 64 + sl * 8);
            acc[n] = __builtin_amdgcn_mfma_f32_16x16x32_bf16(pa, vbv, acc[n], 0, 0, 0);
          }
        }
        __builtin_amdgcn_s_setprio(0);
      }
      __builtin_amdgcn_s_barrier();
      __builtin_amdgcn_sched_barrier(0);
      cur ^= 1;
    }
#pragma unroll
    for (int i = 0; i < 4; ++i) {
      const int row = rbase + lq * 4 + i;
      const float inv = 1.0f / lrow[i];
      bf16* orow = o + ((size_t)(b * 2048 + row)) * 4096 + h * 256;
#pragma unroll
      for (int n = 0; n < 16; ++n) orow[n * 16 + la] = (bf16)(acc[n][i] * inv);
    }
  }
#undef STAGE
}

// ---------------- diagnostic fill if ws too small ----------------
__global__ void fill_err(float* o, int n) {
  int i = blockIdx.x * 256 + threadIdx.x;
  if (i < n) o[i] = 1e9f;
}

extern "C" void kernel_launch(void* const* d_in, const int* in_sizes, int n_in,
                              void* d_out, int out_size, void* d_ws, size_t ws_size,
                              hipStream_t stream) {
  const float* x = (const float*)d_in[0];
  const float* Wq = (const float*)d_in[1];
  const float* Wk = (const float*)d_in[2];
  const float* Wv = (const float*)d_in[3];
  const float* Wo = (const float*)d_in[4];
  const float* kscale = (const float*)d_in[5];
  const float* vscale = (const float*)d_in[6];
  const int* pos = (const int*)d_in[8];
  float* out = (float*)d_out;

  const size_t WS_NEED = 251658240ull;  // 240 MB
  if (ws_size < WS_NEED) {
    fill_err<<<65536, 256, 0, stream>>>(out, out_size);
    return;
  }
  char* ws = (char*)d_ws;
  bf16* x16   = (bf16*)(ws);                  // [4096][4096]   32 MB
  bf16* wqkvt = (bf16*)(ws + 33554432);       // [8192][4096]   64 MB (Q|K|V rows)
  bf16* wot   = (bf16*)(ws + 100663296);      // [4096][4096]   32 MB
  bf16* qkv   = (bf16*)(ws + 134217728);      // [4096][8192]   64 MB (Q|K|V cols)
  bf16* vtb   = (bf16*)(ws + 201326592);      // [2][8][256][2048] 16 MB
  bf16* ao    = (bf16*)(ws + 218103808);      // [4096][4096]   32 MB

  // prep: bf16 conversions + weight transposes (concatenated along N)
  cvt_bf16<<<16384, 256, 0, stream>>>(x, x16, 4194304);
  tconv<<<dim3(64, 64), 256, 0, stream>>>(Wq, wqkvt, 4096, 4096);
  tconv<<<dim3(32, 64), 256, 0, stream>>>(Wk, wqkvt + (size_t)4096 * 4096, 4096, 2048);
  tconv<<<dim3(32, 64), 256, 0, stream>>>(Wv, wqkvt + (size_t)6144 * 4096, 4096, 2048);
  tconv<<<dim3(64, 64), 256, 0, stream>>>(Wo, wot, 4096, 4096);

  // fused QKV projection: [4096][8192] = x16 @ wqkvt^T
  // grid 512: 16x32 btiles; per-XCD chunk = 8 by x 8 bx (ncc_l=2, cbx_l=3)
  gemm256<0><<<512, 512, 0, stream>>>(x16, wqkvt, qkv, 8192, 4096, 2, 3);

  // norms + rope on fused layout (q pre-scaled by 1/sqrt(HD))
  rope_q<<<16384, 256, 0, stream>>>(qkv, pos);
  norm_rope_k<<<8192, 256, 0, stream>>>(qkv + 4096, kscale, pos);
  norm_v<<<8192, 256, 0, stream>>>(qkv + 6144, vscale);
  vtrans<<<dim3(32, 4, 16), 256, 0, stream>>>(qkv + 6144, vtb);

  // attention: paired-qb load-balanced grid (256 blocks = 1/CU)
  flash_attn<<<dim3(16, 8, 2), 512, 0, stream>>>(qkv, vtb, ao);

  // output projection (fp32 out): grid 256: 16x16 btiles; chunk = 8 by x 4 bx
  gemm256<1><<<256, 512, 0, stream>>>(ao, wot, out, 4096, 4096, 2, 2);
}